// Round 12
// baseline (2864.715 us; speedup 1.0000x reference)
//
#include <hip/hip_runtime.h>
#include <math.h>

#define KNN 20
#define NS 0.2f
#define EPSV 1e-6f
#define QT 4
#define OT 8
#define TN 8       // n-tile of final phase
#define CROW 507   // 169*3, cat row stride (floats)
#define SSPLIT 8   // stats splits (== B; split s covers batch s exactly)

struct F3 { float x, y, z; };   // 12-byte vector load (global_load_dwordx3)

extern __shared__ __align__(16) float smem[];

// ---- software grid barrier (single-use slot; all blocks must call) ----
// Safe: __launch_bounds__(256,8) + dynLDS<=18816 guarantee grid <= resident
// capacity (8 blocks/CU x 256 CU = 2048). tid0-only fence+atomic arrive,
// s_sleep spin; __syncthreads brackets order intra-block memory.
__device__ __forceinline__ void gbar(unsigned* cnt, unsigned nb) {
    __syncthreads();
    if (threadIdx.x == 0) {
        __threadfence();                       // release: flush XCD L2 (block's writes)
        atomicAdd(cnt, 1u);
        while (atomicAdd(cnt, 0u) < nb) __builtin_amdgcn_s_sleep(2);
        __threadfence();                       // acquire: invalidate stale lines
    }
    __syncthreads();
}

// ---------------- transpose (B,N,3) -> (B,3,N) + fused sqnorm + barrier-counter zero ----
__global__ void k_transpose(const float* __restrict__ x, float* __restrict__ xt,
                            float* __restrict__ xx, int B, int N,
                            unsigned* __restrict__ bar) {
    if (blockIdx.x == 0 && threadIdx.x < 16) bar[threadIdx.x] = 0u;
    int i = blockIdx.x * blockDim.x + threadIdx.x;
    if (i >= B * N) return;
    int b = i / N, n = i % N;
    const float* src = x + (size_t)(b * N + n) * 3;
    float* dst = xt + (size_t)b * 3 * N + n;
    float s0 = src[0], s1 = src[1], s2 = src[2];
    dst[0] = s0;
    dst[(size_t)N] = s1;
    dst[(size_t)2 * N] = s2;
    float s = 0.f;
    s += s0 * s0;
    s += s1 * s1;
    s += s2 * s2;
    xx[i] = s;
}

// ---------------- persistent per-layer kernel ----------------
// phase 1: blocks [0,mmB) pair-matmul (grid-stride over mmTasks; l==3 uses
//          o-chunked weight staging to fit LDS); blocks [mmB, mmB+1024) knn
//          (8 queries each). All math verbatim R11 -> bit-identical.
// barrier; phase 2: stats (Co*SSPLIT tasks); barrier; phase 3: final fused
// (BN/TN tasks: BN+dir-leaky+mean-pool + catp/catn writes + next-layer sqnorm).
__global__ __launch_bounds__(256, 8)
void k_layer(// knn
             const float* __restrict__ Xn, const float* __restrict__ xx,
             int* __restrict__ idx, int N, int D, long batchStride, long sliceOff,
             // mm
             const float* __restrict__ Xp, const float* __restrict__ W,
             const float* __restrict__ Dw,
             float* __restrict__ U, float* __restrict__ V,
             float* __restrict__ UD, float* __restrict__ VD,
             int C, int Co, int CoP, int TILE, int rowStride, int colOff,
             int mmB, int mmTasks, int chunked,
             // stats + final
             float* __restrict__ partials,
             const float* __restrict__ gamma, const float* __restrict__ beta,
             float* __restrict__ catp, float* __restrict__ catn,
             float* __restrict__ xxout, int colOffOut, float cnt, int doSq,
             int BN, unsigned* __restrict__ bar, int slot) {
    float* sm = smem;
    int tid = threadIdx.x;
    int bid = (int)blockIdx.x;
    int nb = (int)gridDim.x;

    // ================= phase 1: mm | knn =================
    if (bid < mmB) {
        int C3 = C * 3;
        for (int task = bid; task < mmTasks; task += mmB) {
            __syncthreads();                    // protect LDS reuse across tasks
            int bn0 = task * TILE;
            if (!chunked) {
                const int CP = C * CoP;
                float* wts = sm;
                float* xs = sm + 4 * CP;
                int npad = CoP - Co;
                if (npad) {
                    for (int t = tid; t < 4 * C * npad; t += 256) {
                        int q = t / npad, oo = Co + t % npad;
                        int mat = q / C, c = q % C;
                        wts[mat * CP + c * CoP + oo] = 0.f;
                    }
                }
                int twoCC = 2 * C * Co;
                for (int t = tid; t < twoCC; t += 256) {
                    int o = t / (2 * C), c = t % (2 * C);
                    float w = W[t], dw = Dw[t];
                    if (c < C) {
                        wts[c * CoP + o] = w;
                        wts[2 * CP + c * CoP + o] = dw;
                    } else {
                        wts[CP + (c - C) * CoP + o] = w;
                        wts[3 * CP + (c - C) * CoP + o] = dw;
                    }
                }
                for (int t = tid; t < TILE * C3; t += 256) {
                    int p = t / C3, cc = t % C3;
                    xs[t] = Xp[(size_t)(bn0 + p) * rowStride + colOff + cc];
                }
                __syncthreads();
                for (int t = tid; t < CP; t += 256) {
                    wts[CP + t] -= wts[t];
                    wts[3 * CP + t] -= wts[2 * CP + t];
                }
                __syncthreads();

                int GPP = CoP >> 2;
                int items = TILE * GPP;
                for (int e = tid; e < items; e += 256) {
                    int p = e / GPP, og = e - p * GPP;
                    int o0 = og * 4;
                    const float* xr = xs + p * C3;
                    float aU[4][3], aV[4][3], aDu[4][3], aDv[4][3];
#pragma unroll
                    for (int i = 0; i < 4; ++i)
#pragma unroll
                        for (int j = 0; j < 3; ++j) {
                            aU[i][j] = 0.f; aV[i][j] = 0.f; aDu[i][j] = 0.f; aDv[i][j] = 0.f;
                        }
                    for (int c = 0; c < C; ++c) {
                        float x0 = xr[c * 3], x1 = xr[c * 3 + 1], x2 = xr[c * 3 + 2];
                        const float* wp = wts + c * CoP + o0;
                        float4 wa4 = *(const float4*)(wp);
                        float4 wb4 = *(const float4*)(wp + CP);
                        float4 da4 = *(const float4*)(wp + 2 * CP);
                        float4 db4 = *(const float4*)(wp + 3 * CP);
                        float wav[4] = {wa4.x, wa4.y, wa4.z, wa4.w};
                        float wbv[4] = {wb4.x, wb4.y, wb4.z, wb4.w};
                        float dav[4] = {da4.x, da4.y, da4.z, da4.w};
                        float dbv[4] = {db4.x, db4.y, db4.z, db4.w};
#pragma unroll
                        for (int i = 0; i < 4; ++i) {
                            aU[i][0] += wav[i] * x0; aU[i][1] += wav[i] * x1; aU[i][2] += wav[i] * x2;
                            aV[i][0] += wbv[i] * x0; aV[i][1] += wbv[i] * x1; aV[i][2] += wbv[i] * x2;
                            aDu[i][0] += dav[i] * x0; aDu[i][1] += dav[i] * x1; aDu[i][2] += dav[i] * x2;
                            aDv[i][0] += dbv[i] * x0; aDv[i][1] += dbv[i] * x1; aDv[i][2] += dbv[i] * x2;
                        }
                    }
                    size_t base = ((size_t)(bn0 + p) * Co + o0) * 3;
#pragma unroll
                    for (int i = 0; i < 4; ++i) {
                        int o = o0 + i;
                        if (o < Co) {
                            size_t off = base + (size_t)i * 3;
                            U[off] = aU[i][0]; U[off + 1] = aU[i][1]; U[off + 2] = aU[i][2];
                            V[off] = aV[i][0]; V[off + 1] = aV[i][1]; V[off + 2] = aV[i][2];
                            UD[off] = aDu[i][0]; UD[off + 1] = aDu[i][1]; UD[off + 2] = aDu[i][2];
                            VD[off] = aDv[i][0]; VD[off + 1] = aDv[i][1]; VD[off + 2] = aDv[i][2];
                        }
                    }
                }
            } else {
                // o-chunked variant (L4): same staged values / chains / writes
                float* xs = sm + 4 * (C * 24);   // xs after max chunk wts
                for (int t = tid; t < TILE * C3; t += 256) {
                    int p = t / C3, cc = t % C3;
                    xs[t] = Xp[(size_t)(bn0 + p) * rowStride + colOff + cc];
                }
                for (int o0c = 0; o0c < CoP; o0c += 24) {
                    int och = CoP - o0c; if (och > 24) och = 24;
                    int CPc = C * och;
                    float* wts = sm;
                    __syncthreads();
                    for (int t = tid; t < 4 * CPc; t += 256) {
                        int mat = t / CPc; int r = t - mat * CPc;
                        int c = r / och; int oo = r - c * och;
                        int o = o0c + oo;
                        const float* srcw = (mat < 2) ? W : Dw;
                        int cc = (mat & 1) ? (C + c) : c;
                        wts[mat * CPc + c * och + oo] =
                            (o < Co) ? srcw[(size_t)o * 2 * C + cc] : 0.f;
                    }
                    __syncthreads();
                    for (int t = tid; t < CPc; t += 256) {
                        wts[CPc + t] -= wts[t];
                        wts[3 * CPc + t] -= wts[2 * CPc + t];
                    }
                    __syncthreads();
                    int GPP = och >> 2;
                    int items = TILE * GPP;
                    for (int e = tid; e < items; e += 256) {
                        int p = e / GPP, og = e - p * GPP;
                        int o0 = og * 4;
                        const float* xr = xs + p * C3;
                        float aU[4][3], aV[4][3], aDu[4][3], aDv[4][3];
#pragma unroll
                        for (int i = 0; i < 4; ++i)
#pragma unroll
                            for (int j = 0; j < 3; ++j) {
                                aU[i][j] = 0.f; aV[i][j] = 0.f; aDu[i][j] = 0.f; aDv[i][j] = 0.f;
                            }
                        for (int c = 0; c < C; ++c) {
                            float x0 = xr[c * 3], x1 = xr[c * 3 + 1], x2 = xr[c * 3 + 2];
                            const float* wp = wts + c * och + o0;
                            float4 wa4 = *(const float4*)(wp);
                            float4 wb4 = *(const float4*)(wp + CPc);
                            float4 da4 = *(const float4*)(wp + 2 * CPc);
                            float4 db4 = *(const float4*)(wp + 3 * CPc);
                            float wav[4] = {wa4.x, wa4.y, wa4.z, wa4.w};
                            float wbv[4] = {wb4.x, wb4.y, wb4.z, wb4.w};
                            float dav[4] = {da4.x, da4.y, da4.z, da4.w};
                            float dbv[4] = {db4.x, db4.y, db4.z, db4.w};
#pragma unroll
                            for (int i = 0; i < 4; ++i) {
                                aU[i][0] += wav[i] * x0; aU[i][1] += wav[i] * x1; aU[i][2] += wav[i] * x2;
                                aV[i][0] += wbv[i] * x0; aV[i][1] += wbv[i] * x1; aV[i][2] += wbv[i] * x2;
                                aDu[i][0] += dav[i] * x0; aDu[i][1] += dav[i] * x1; aDu[i][2] += dav[i] * x2;
                                aDv[i][0] += dbv[i] * x0; aDv[i][1] += dbv[i] * x1; aDv[i][2] += dbv[i] * x2;
                            }
                        }
                        size_t base = ((size_t)(bn0 + p) * Co + (o0c + o0)) * 3;
#pragma unroll
                        for (int i = 0; i < 4; ++i) {
                            int o = o0c + o0 + i;
                            if (o < Co) {
                                size_t off = base + (size_t)i * 3;
                                U[off] = aU[i][0]; U[off + 1] = aU[i][1]; U[off + 2] = aU[i][2];
                                V[off] = aV[i][0]; V[off + 1] = aV[i][1]; V[off + 2] = aV[i][2];
                                UD[off] = aDu[i][0]; UD[off + 1] = aDu[i][1]; UD[off + 2] = aDu[i][2];
                                VD[off] = aDv[i][0]; VD[off + 1] = aDv[i][1]; VD[off + 2] = aDv[i][2];
                            }
                        }
                    }
                }
            }
        }
    } else {
        // ---------------- knn body (R11 verbatim), 8 queries/block ----------------
        int kb = bid - mmB;
        int qbpb = N / 8;
        int b = kb / qbpb;
        int qbase = (kb - b * qbpb) * 8;
        int lane = tid & 63;
        int wave = tid >> 6;

        float* qf = sm;
        float* pdb = sm + 128 * QT;

        const float* Xb = Xn + (size_t)b * batchStride + sliceOff;
        const float* xxb = xx + (size_t)b * N;

        for (int q0 = qbase; q0 < qbase + 8; q0 += QT) {
            for (int t = tid; t < QT * D; t += 256) {
                int d = t >> 2, q = t & 3;
                qf[d * QT + q] = Xb[(size_t)d * N + (q0 + q)];
            }
            __syncthreads();

            float a0x = 0.f, a0y = 0.f, a0z = 0.f, a0w = 0.f;
            float a1x = 0.f, a1y = 0.f, a1z = 0.f, a1w = 0.f;
            float a2x = 0.f, a2y = 0.f, a2z = 0.f, a2w = 0.f;
            float a3x = 0.f, a3y = 0.f, a3z = 0.f, a3w = 0.f;

            const float* mbase = Xb + 4 * tid;
#pragma unroll 3
            for (int d = 0; d < D; ++d) {
                float4 xm = *(const float4*)(mbase + (size_t)d * N);
                float4 qv = *(const float4*)(qf + d * QT);
                a0x += qv.x * xm.x; a0y += qv.x * xm.y; a0z += qv.x * xm.z; a0w += qv.x * xm.w;
                a1x += qv.y * xm.x; a1y += qv.y * xm.y; a1z += qv.y * xm.z; a1w += qv.y * xm.w;
                a2x += qv.z * xm.x; a2y += qv.z * xm.y; a2z += qv.z * xm.z; a2w += qv.z * xm.w;
                a3x += qv.w * xm.x; a3y += qv.w * xm.y; a3z += qv.w * xm.z; a3w += qv.w * xm.w;
            }

            {
                float4 m2 = *(const float4*)(xxb + 4 * tid);
                float4 qn = *(const float4*)(xxb + q0);
                float4 v;
                v.x = 2.f * a0x - qn.x - m2.x; v.y = 2.f * a0y - qn.x - m2.y;
                v.z = 2.f * a0z - qn.x - m2.z; v.w = 2.f * a0w - qn.x - m2.w;
                *(float4*)(pdb + 0 * 1024 + 4 * tid) = v;
                v.x = 2.f * a1x - qn.y - m2.x; v.y = 2.f * a1y - qn.y - m2.y;
                v.z = 2.f * a1z - qn.y - m2.z; v.w = 2.f * a1w - qn.y - m2.w;
                *(float4*)(pdb + 1 * 1024 + 4 * tid) = v;
                v.x = 2.f * a2x - qn.z - m2.x; v.y = 2.f * a2y - qn.z - m2.y;
                v.z = 2.f * a2z - qn.z - m2.z; v.w = 2.f * a2w - qn.z - m2.w;
                *(float4*)(pdb + 2 * 1024 + 4 * tid) = v;
                v.x = 2.f * a3x - qn.w - m2.x; v.y = 2.f * a3y - qn.w - m2.y;
                v.z = 2.f * a3z - qn.w - m2.z; v.w = 2.f * a3w - qn.w - m2.w;
                *(float4*)(pdb + 3 * 1024 + 4 * tid) = v;
            }
            __syncthreads();

            unsigned long long key[16];
#pragma unroll
            for (int t = 0; t < 16; ++t) {
                unsigned u = __float_as_uint(pdb[wave * 1024 + t * 64 + lane]);
                u ^= (unsigned)((int)u >> 31) | 0x80000000u;
                unsigned lo = (unsigned)(1023 - t * 64) - (unsigned)lane;
                key[t] = ((unsigned long long)u << 32) | (unsigned long long)lo;
            }

#define CE(a, b)                                          \
            {                                             \
                unsigned long long ka = key[a], kb2 = key[b]; \
                bool sw = ka < kb2;                       \
                key[a] = sw ? kb2 : ka;                   \
                key[b] = sw ? ka : kb2;                   \
            }
            CE(0,1) CE(2,3) CE(4,5) CE(6,7) CE(8,9) CE(10,11) CE(12,13) CE(14,15)
            CE(0,2) CE(1,3) CE(4,6) CE(5,7) CE(8,10) CE(9,11) CE(12,14) CE(13,15)
            CE(1,2) CE(5,6) CE(9,10) CE(13,14)
            CE(0,4) CE(1,5) CE(2,6) CE(3,7) CE(8,12) CE(9,13) CE(10,14) CE(11,15)
            CE(2,4) CE(3,5) CE(10,12) CE(11,13)
            CE(1,2) CE(3,4) CE(5,6) CE(9,10) CE(11,12) CE(13,14)
            CE(0,8) CE(1,9) CE(2,10) CE(3,11) CE(4,12) CE(5,13) CE(6,14) CE(7,15)
            CE(4,8) CE(5,9) CE(6,10) CE(7,11)
            CE(2,4) CE(3,5) CE(6,8) CE(7,9) CE(10,12) CE(11,13)
            CE(1,2) CE(3,4) CE(5,6) CE(7,8) CE(9,10) CE(11,12) CE(13,14)
#undef CE

            __syncthreads();
            unsigned long long* kl = (unsigned long long*)(pdb + wave * 1024);
#pragma unroll
            for (int t = 8; t < 16; ++t) kl[(t - 8) * 64 + lane] = key[t];
            int nspill = 0;

            long outBase = ((long)b * N + q0 + wave) * KNN;
            for (int it = 0; it < KNN; ++it) {
                unsigned myh = (unsigned)(key[0] >> 32);
                unsigned mylo = (unsigned)(key[0] & 0xFFFFFFFFull);
                unsigned bh = myh;
#pragma unroll
                for (int off = 32; off >= 1; off >>= 1) {
                    unsigned oh = __shfl_xor(bh, off, 64);
                    if (oh > bh) bh = oh;
                }
                unsigned long long mask = __ballot(myh == bh);
                unsigned ml;
                if (__popcll(mask) == 1) {
                    int src = (int)(__ffsll((long long)mask) - 1);
                    ml = __shfl(mylo, src, 64);
                } else {
                    unsigned cand = (myh == bh) ? mylo : 0u;
#pragma unroll
                    for (int off = 32; off >= 1; off >>= 1) {
                        unsigned oc = __shfl_xor(cand, off, 64);
                        if (oc > cand) cand = oc;
                    }
                    ml = cand;
                }
                int bi = 1023 - (int)(ml & 1023u);
                if (lane == 0) idx[outBase + it] = bi;
                if ((bi & 63) == lane) {
                    key[0] = key[1]; key[1] = key[2]; key[2] = key[3]; key[3] = key[4];
                    key[4] = key[5]; key[5] = key[6]; key[6] = key[7];
                    int sidx = nspill < 8 ? nspill : 7;
                    unsigned long long nv = kl[sidx * 64 + lane];
                    key[7] = (nspill < 8) ? nv : 0ull;
                    nspill++;
                }
            }
            __syncthreads();
        }
    }

    gbar(bar + slot, (unsigned)nb);

    // ================= phase 2: stats (R11 verbatim per task) =================
    {
        float* Ush = sm;             // 3072
        float* r1 = sm + 3072;       // 256
        float* r2 = sm + 3328;       // 256
        int P = BN / SSPLIT;
        for (int task = bid; task < Co * SSPLIT; task += nb) {
            int o = task % Co;
            int s = task / Co;
            int g0 = s * P;
            __syncthreads();
            for (int t = tid; t < P; t += 256) {
                F3 u3 = *(const F3*)(U + ((size_t)(g0 + t) * Co + o) * 3);
                Ush[t * 3 + 0] = u3.x;
                Ush[t * 3 + 1] = u3.y;
                Ush[t * 3 + 2] = u3.z;
            }
            __syncthreads();
            float s1 = 0.f, s2 = 0.f;
            for (int pl = tid; pl < P; pl += 256) {
                int g = g0 + pl;
                F3 v3 = *(const F3*)(V + ((size_t)g * Co + o) * 3);
                float v0 = v3.x, v1 = v3.y, v2 = v3.z;
                const int* ip = idx + (size_t)g * KNN;
                for (int kk = 0; kk < KNN; ++kk) {
                    const float* Ur = Ush + ip[kk] * 3;
                    float p0 = Ur[0] + v0;
                    float p1 = Ur[1] + v1;
                    float p2 = Ur[2] + v2;
                    float nm = sqrtf(p0 * p0 + p1 * p1 + p2 * p2) + EPSV;
                    s1 += nm;
                    s2 += nm * nm;
                }
            }
            r1[tid] = s1; r2[tid] = s2;
            __syncthreads();
            for (int st = 128; st > 0; st >>= 1) {
                if (tid < st) { r1[tid] += r1[tid + st]; r2[tid] += r2[tid + st]; }
                __syncthreads();
            }
            if (tid == 0) {
                partials[(o * SSPLIT + s) * 2] = r1[0];
                partials[(o * SSPLIT + s) * 2 + 1] = r2[0];
            }
        }
    }

    gbar(bar + slot + 1, (unsigned)nb);

    // ================= phase 3: final fused (R11 verbatim per task) =================
    {
        int CC = Co * 3;
        float* tile = sm;                  // TN*255 max 2040
        float* muS = sm + TN * 255;        // 85
        float* invS = muS + 85;            // 85
        int ftasks = (N / TN) * 8;         // B == 8
        const float invk = 1.f / (float)KNN;
        for (int task = bid; task < ftasks; task += nb) {
            int nt = N / TN;
            int b = task / nt;
            int n0 = (task - b * nt) * TN;
            __syncthreads();
            for (int o = tid; o < Co; o += 256) {
                float s1 = 0.f, s2 = 0.f;
                for (int s = 0; s < SSPLIT; ++s) {
                    s1 += partials[(o * SSPLIT + s) * 2];
                    s2 += partials[(o * SSPLIT + s) * 2 + 1];
                }
                float mu = s1 / cnt;
                float var = s2 / cnt - mu * mu;
                muS[o] = mu;
                invS[o] = rsqrtf(var + 1e-5f);
            }
            __syncthreads();
            int items = TN * Co;
            for (int e = tid; e < items; e += 256) {
                int nl = e / Co, o = e - nl * Co;
                int n = n0 + nl;
                float mu = muS[o], inv = invS[o];
                float gmm = gamma[o], bt = beta[o];
                size_t ctr = ((size_t)(b * N + n) * Co + o) * 3;
                F3 vc = *(const F3*)(V + ctr);
                F3 wc = *(const F3*)(VD + ctr);
                float v0 = vc.x, v1 = vc.y, v2 = vc.z;
                float w0 = wc.x, w1 = wc.y, w2 = wc.z;
                const int* ip = idx + ((size_t)b * N + n) * KNN;
                float a0 = 0.f, a1 = 0.f, a2 = 0.f;
                for (int kk = 0; kk < KNN; ++kk) {
                    int m = ip[kk];
                    size_t nbx = ((size_t)(b * N + m) * Co + o) * 3;
                    F3 un = *(const F3*)(U + nbx);
                    F3 dn = *(const F3*)(UD + nbx);
                    float p0 = un.x + v0;
                    float p1 = un.y + v1;
                    float p2 = un.z + v2;
                    float nm = sqrtf(p0 * p0 + p1 * p1 + p2 * p2) + EPSV;
                    float nbn = (nm - mu) * inv * gmm + bt;
                    float sc = nbn / nm;
                    p0 *= sc; p1 *= sc; p2 *= sc;
                    float d0 = dn.x + w0;
                    float d1 = dn.y + w1;
                    float d2 = dn.z + w2;
                    float dot = p0 * d0 + p1 * d1 + p2 * d2;
                    if (dot >= 0.f) {
                        a0 += p0; a1 += p1; a2 += p2;
                    } else {
                        float f = dot / (d0 * d0 + d1 * d1 + d2 * d2 + EPSV);
                        a0 += NS * p0 + (1.f - NS) * (p0 - f * d0);
                        a1 += NS * p1 + (1.f - NS) * (p1 - f * d1);
                        a2 += NS * p2 + (1.f - NS) * (p2 - f * d2);
                    }
                }
                tile[nl * CC + o * 3 + 0] = a0 * invk;
                tile[nl * CC + o * 3 + 1] = a1 * invk;
                tile[nl * CC + o * 3 + 2] = a2 * invk;
            }
            __syncthreads();
            for (int t = tid; t < TN * CC; t += 256) {
                int nl = t / CC, c = t - nl * CC;
                catp[(size_t)(b * N + n0 + nl) * CROW + colOffOut + c] = tile[nl * CC + c];
            }
            for (int t = tid; t < TN * CC; t += 256) {
                int c = t >> 3, nl = t & (TN - 1);
                catn[(size_t)b * CROW * N + (size_t)(colOffOut + c) * N + n0 + nl] = tile[nl * CC + c];
            }
            if (doSq && tid < TN) {
                const float* row = tile + tid * CC;
                float s = 0.f;
                for (int c = 0; c < CC; ++c) {
                    float v = row[c];
                    s += v * v;
                }
                xxout[(size_t)b * N + n0 + tid] = s;
            }
        }
    }
}

// ---------------- persistent layer-5 kernel: matmul -> stats -> final ----------------
__global__ __launch_bounds__(256, 8)
void k_layer5(const float* __restrict__ X, const float* __restrict__ W,
              const float* __restrict__ Dw,
              float* __restrict__ U, float* __restrict__ Ud, float* __restrict__ mv,
              const float* __restrict__ gamma, const float* __restrict__ beta,
              float* __restrict__ out, int N, int BN,
              unsigned* __restrict__ bar, int slot) {
    const int Cin = 169, Cout = 341;
    const long batchStride = (long)CROW * N;
    int tid = threadIdx.x;
    int bid = (int)blockIdx.x;
    int nb = (int)gridDim.x;
    float* sm = smem;

    // ---- phase 1: matmul (j-fused, 2-n tile), 2 x 44 x 8 tasks ----
    {
        const int OTILES = 44;    // 43 W tiles + 1 Dw tile
        int tasks = 2 * OTILES * 8;
        for (int task = bid; task < tasks; task += nb) {
            int nx = task & 1;
            int r = task >> 1;
            int ot = r % OTILES;
            int b = r / OTILES;
            int n = nx * 512 + 2 * tid;

            const float* Wp; float* Up; int CoutE; int o0;
            if (ot == OTILES - 1) { Wp = Dw; Up = Ud; CoutE = 1; o0 = 0; }
            else { Wp = W; Up = U; CoutE = Cout; o0 = ot * OT; }

            float* wsm = sm;   // OT rows x 176 stride
            __syncthreads();
            for (int t = tid; t < OT * Cin; t += 256) {
                int oo = t / Cin, c = t % Cin;
                int o = o0 + oo;
                wsm[oo * 176 + c] = (o < CoutE) ? Wp[(size_t)o * Cin + c] : 0.f;
            }
            __syncthreads();

            const float* Xp = X + (size_t)b * batchStride + n;
            float au[OT][3][2];
#pragma unroll
            for (int oo = 0; oo < OT; ++oo)
#pragma unroll
                for (int j = 0; j < 3; ++j) {
                    au[oo][j][0] = 0.f; au[oo][j][1] = 0.f;
                }
            int c = 0;
            for (; c + 4 <= Cin; c += 4) {
                float2 xv[4][3];
#pragma unroll
                for (int cc = 0; cc < 4; ++cc)
#pragma unroll
                    for (int j = 0; j < 3; ++j)
                        xv[cc][j] = *(const float2*)(Xp + ((size_t)(c + cc) * 3 + j) * N);
#pragma unroll
                for (int oo = 0; oo < OT; ++oo) {
                    float4 w4 = *(const float4*)&wsm[oo * 176 + c];
                    float wv[4] = {w4.x, w4.y, w4.z, w4.w};
#pragma unroll
                    for (int j = 0; j < 3; ++j) {
#pragma unroll
                        for (int cc = 0; cc < 4; ++cc) {
                            au[oo][j][0] += wv[cc] * xv[cc][j].x;
                            au[oo][j][1] += wv[cc] * xv[cc][j].y;
                        }
                    }
                }
            }
            for (; c < Cin; ++c) {
                float2 xv[3];
#pragma unroll
                for (int j = 0; j < 3; ++j)
                    xv[j] = *(const float2*)(Xp + ((size_t)c * 3 + j) * N);
#pragma unroll
                for (int oo = 0; oo < OT; ++oo) {
                    float wv = wsm[oo * 176 + c];
#pragma unroll
                    for (int j = 0; j < 3; ++j) {
                        au[oo][j][0] += wv * xv[j].x;
                        au[oo][j][1] += wv * xv[j].y;
                    }
                }
            }
#pragma unroll
            for (int oo = 0; oo < OT; ++oo) {
                int o = o0 + oo;
                if (o < CoutE) {
#pragma unroll
                    for (int j = 0; j < 3; ++j) {
                        float2 st; st.x = au[oo][j][0]; st.y = au[oo][j][1];
                        *(float2*)&Up[(((size_t)b * CoutE + o) * 3 + j) * N + n] = st;
                    }
                }
            }
        }
    }

    gbar(bar + slot, (unsigned)nb);

    // ---- phase 2: stats (one task per channel, 341) ----
    {
        float* r1 = sm;
        float* r2 = sm + 256;
        float cntf = (float)BN;
        for (int o = bid; o < Cout; o += nb) {
            __syncthreads();
            float s1 = 0.f, s2 = 0.f;
            for (int g = tid; g < BN; g += 256) {
                int b = g / N, n = g % N;
                const float* Ub = U + (((size_t)b * Cout + o) * 3) * N;
                float p0 = Ub[n], p1 = Ub[(size_t)N + n], p2 = Ub[(size_t)2 * N + n];
                float nm = sqrtf(p0 * p0 + p1 * p1 + p2 * p2) + EPSV;
                s1 += nm;
                s2 += nm * nm;
            }
            r1[tid] = s1; r2[tid] = s2;
            __syncthreads();
            for (int st = 128; st > 0; st >>= 1) {
                if (tid < st) { r1[tid] += r1[tid + st]; r2[tid] += r2[tid + st]; }
                __syncthreads();
            }
            if (tid == 0) {
                float mu = r1[0] / cntf;
                float var = r2[0] / cntf - mu * mu;
                mv[2 * o] = mu;
                mv[2 * o + 1] = rsqrtf(var + 1e-5f);
            }
        }
    }

    gbar(bar + slot + 1, (unsigned)nb);

    // ---- phase 3: final (4 x 341 x 8 tasks) ----
    {
        int tasks = 4 * Cout * 8;
        for (int task = bid; task < tasks; task += nb) {
            int nx = task & 3;
            int r = task >> 2;
            int o = r % Cout;
            int b = r / Cout;
            int n = nx * 256 + tid;
            float mu = mv[2 * o];
            float inv = mv[2 * o + 1];
            float g = gamma[o], bt = beta[o];

            const float* Ub = U + (((size_t)b * Cout + o) * 3) * N;
            float p0 = Ub[n], p1 = Ub[(size_t)N + n], p2 = Ub[(size_t)2 * N + n];
            float nm = sqrtf(p0 * p0 + p1 * p1 + p2 * p2) + EPSV;
            float nbn = (nm - mu) * inv * g + bt;
            float sc = nbn / nm;
            p0 *= sc; p1 *= sc; p2 *= sc;

            float d0 = Ud[((size_t)b * 3 + 0) * N + n];
            float d1 = Ud[((size_t)b * 3 + 1) * N + n];
            float d2 = Ud[((size_t)b * 3 + 2) * N + n];
            float dot = p0 * d0 + p1 * d1 + p2 * d2;
            float o0, o1, o2;
            if (dot >= 0.f) {
                o0 = p0; o1 = p1; o2 = p2;
            } else {
                float f = dot / (d0 * d0 + d1 * d1 + d2 * d2 + EPSV);
                o0 = NS * p0 + (1.f - NS) * (p0 - f * d0);
                o1 = NS * p1 + (1.f - NS) * (p1 - f * d1);
                o2 = NS * p2 + (1.f - NS) * (p2 - f * d2);
            }
            size_t ob = (((size_t)b * Cout + o) * 3) * N + n;
            out[ob] = o0;
            out[ob + (size_t)N] = o1;
            out[ob + (size_t)2 * N] = o2;
        }
    }
}

extern "C" void kernel_launch(void* const* d_in, const int* in_sizes, int n_in,
                              void* d_out, int out_size, void* d_ws, size_t ws_size,
                              hipStream_t stream) {
    (void)in_sizes; (void)n_in; (void)out_size; (void)ws_size;
    const int B = 8, N = 1024;

    const float* x = (const float*)d_in[0];
    const float* W[5]; const float* Dw[5]; const float* G[5]; const float* Bt[5];
    for (int l = 0; l < 5; ++l) {
        W[l]  = (const float*)d_in[1 + 4 * l];
        Dw[l] = (const float*)d_in[2 + 4 * l];
        G[l]  = (const float*)d_in[3 + 4 * l];
        Bt[l] = (const float*)d_in[4 + 4 * l];
    }

    float* ws = (float*)d_ws;
    size_t off = 0;
    float* xt = ws + off;     off += (size_t)B * 3 * N;
    int* idx = (int*)(ws + off); off += (size_t)B * N * KNN;
    float* catp = ws + off;   off += (size_t)B * N * CROW;
    float* catn = ws + off;   off += (size_t)B * N * CROW;
    float* Up = ws + off;     off += (size_t)B * N * 85 * 3;
    float* Vp = ws + off;     off += (size_t)B * N * 85 * 3;
    float* UDp = ws + off;    off += (size_t)B * N * 85 * 3;
    float* VDp = ws + off;    off += (size_t)B * N * 85 * 3;
    float* U5 = ws + off;     off += (size_t)B * 341 * 3 * N;
    float* d5buf = ws + off;  off += (size_t)B * 3 * N;
    float* xx = ws + off;     off += (size_t)B * N;
    float* partials = ws + off; off += (size_t)341 * SSPLIT * 2;
    float* mv = ws + off;     off += 2 * 341;
    unsigned* bar = (unsigned*)(ws + off); off += 16;

    k_transpose<<<(B * N + 255) / 256, 256, 0, stream>>>(x, xt, xx, B, N, bar);

    const int Cin_[4]  = {1, 21, 21, 42};
    const int Cout_[4] = {21, 21, 42, 85};
    const int inOff_[4] = {-1, 0, 21, 42};
    const int outOff_[4] = {0, 21, 42, 84};
    const int Tile_[4] = {32, 32, 16, 4};

    const int BN = B * N;

    for (int l = 0; l < 4; ++l) {
        int C = Cin_[l], Co = Cout_[l];
        int D = C * 3;
        int CoP = (Co + 3) & ~3;
        int TILE = Tile_[l];
        int chunked = (l == 3) ? 1 : 0;
        int mmB = (l == 3) ? 512 : 256;
        int mmTasks = BN / TILE;

        const float* Xn; long bs, so;
        if (inOff_[l] < 0) { Xn = xt; bs = (long)3 * N; so = 0; }
        else { Xn = catn; bs = (long)CROW * N; so = (long)inOff_[l] * 3 * N; }

        const float* Xp; int rs, co;
        if (inOff_[l] < 0) { Xp = x; rs = 3; co = 0; }
        else { Xp = catp; rs = CROW; co = inOff_[l] * 3; }

        // dyn LDS: max over phases (knn 18432; mm: l2 18816, l3 chunk 18144)
        size_t mmNeed = chunked
            ? (size_t)(4 * C * 24 + TILE * C * 3) * sizeof(float)
            : (size_t)(4 * C * CoP + TILE * C * 3) * sizeof(float);
        size_t dynLDS = mmNeed > 18432 ? mmNeed : 18432;

        int doSq = (l < 3) ? 1 : 0;
        dim3 grid(mmB + 1024);
        k_layer<<<grid, 256, dynLDS, stream>>>(
            Xn, xx, idx, N, D, bs, so,
            Xp, W[l], Dw[l], Up, Vp, UDp, VDp,
            C, Co, CoP, TILE, rs, co, mmB, mmTasks, chunked,
            partials, G[l], Bt[l], catp, catn, xx,
            outOff_[l] * 3, (float)((size_t)BN * KNN), doSq,
            BN, bar, 2 * l);
    }

    k_layer5<<<1280, 256, 5632, stream>>>(
        catn, W[4], Dw[4], U5, d5buf, mv, G[4], Bt[4],
        (float*)d_out, N, BN, bar, 8);
}

// Round 13
// 672.687 us; speedup vs baseline: 4.2586x; 4.2586x over previous
//
#include <hip/hip_runtime.h>
#include <math.h>

#define KNN 20
#define NS 0.2f
#define EPSV 1e-6f
#define QT 4
#define OT 8
#define TN 8       // n-tile of k_final_fused
#define OCH 12     // L4 mm o-chunk width
#define CROW 507   // 169*3, cat row stride (floats)
#define SSPLIT 8   // stats splits (== B; split s covers batch s exactly)

struct F3 { float x, y, z; };   // 12-byte vector load (global_load_dwordx3)

extern __shared__ __align__(16) float smem[];

// ---------------- transpose (B,N,3) -> (B,3,N) + fused sqnorm (layer-1) ----------------
__global__ void k_transpose(const float* __restrict__ x, float* __restrict__ xt,
                            float* __restrict__ xx, int B, int N) {
    int i = blockIdx.x * blockDim.x + threadIdx.x;
    if (i >= B * N) return;
    int b = i / N, n = i % N;
    const float* src = x + (size_t)(b * N + n) * 3;
    float* dst = xt + (size_t)b * 3 * N + n;
    float s0 = src[0], s1 = src[1], s2 = src[2];
    dst[0] = s0;
    dst[(size_t)N] = s1;
    dst[(size_t)2 * N] = s2;
    float s = 0.f;
    s += s0 * s0;
    s += s1 * s1;
    s += s2 * s2;
    xx[i] = s;
}

// ---------------- fused knn + pair-matmul launch ----------------
// Blocks [0, mmBlocks) run the pair-matmul body (chunked==1: o-chunked weight
// staging, OCH-wide, for the L4 shapes that don't fit LDS whole); blocks
// [mmBlocks, ...) run knn, 8 queries each (two QT passes). mm executes in
// knn's occupancy shadow. All per-query / per-point math verbatim from R11;
// chunked staging verified bit-identical on HW in R12 -> bit-identical.
__global__ void k_knn_mm(// knn args
                         const float* __restrict__ Xn, const float* __restrict__ xx,
                         int* __restrict__ idx, int N, int D,
                         long batchStride, long sliceOff, int qPerBlock,
                         // mm args
                         const float* __restrict__ Xp, const float* __restrict__ W,
                         const float* __restrict__ Dw,
                         float* __restrict__ U, float* __restrict__ V,
                         float* __restrict__ UD, float* __restrict__ VD,
                         int C, int Co, int CoP, int TILE,
                         int rowStride, int colOff, int mmBlocks, int chunked) {
    float* sm = smem;
    int tid = threadIdx.x;

    if ((int)blockIdx.x < mmBlocks) {
        int C3 = C * 3;
        int bn0 = blockIdx.x * TILE;
        if (!chunked) {
            // ---------------- whole-weight pair-matmul (R11 verbatim) ----------------
            const int CP = C * CoP;
            float* wts = sm;            // 4*CP
            float* xs = sm + 4 * CP;    // TILE * C * 3

            int npad = CoP - Co;
            if (npad) {
                for (int t = tid; t < 4 * C * npad; t += 256) {
                    int q = t / npad, oo = Co + t % npad;
                    int mat = q / C, c = q % C;
                    wts[mat * CP + c * CoP + oo] = 0.f;
                }
            }
            int twoCC = 2 * C * Co;
            for (int t = tid; t < twoCC; t += 256) {
                int o = t / (2 * C), c = t % (2 * C);
                float w = W[t], dw = Dw[t];
                if (c < C) {
                    wts[c * CoP + o] = w;
                    wts[2 * CP + c * CoP + o] = dw;
                } else {
                    wts[CP + (c - C) * CoP + o] = w;
                    wts[3 * CP + (c - C) * CoP + o] = dw;
                }
            }
            for (int t = tid; t < TILE * C3; t += 256) {
                int p = t / C3, cc = t % C3;
                xs[t] = Xp[(size_t)(bn0 + p) * rowStride + colOff + cc];
            }
            __syncthreads();
            for (int t = tid; t < CP; t += 256) {
                wts[CP + t] -= wts[t];
                wts[3 * CP + t] -= wts[2 * CP + t];
            }
            __syncthreads();

            int GPP = CoP >> 2;
            int items = TILE * GPP;
            for (int e = tid; e < items; e += 256) {
                int p = e / GPP, og = e - p * GPP;
                int o0 = og * 4;
                const float* xr = xs + p * C3;

                float aU[4][3], aV[4][3], aDu[4][3], aDv[4][3];
#pragma unroll
                for (int i = 0; i < 4; ++i)
#pragma unroll
                    for (int j = 0; j < 3; ++j) {
                        aU[i][j] = 0.f; aV[i][j] = 0.f; aDu[i][j] = 0.f; aDv[i][j] = 0.f;
                    }

                for (int c = 0; c < C; ++c) {
                    float x0 = xr[c * 3], x1 = xr[c * 3 + 1], x2 = xr[c * 3 + 2];
                    const float* wp = wts + c * CoP + o0;
                    float4 wa4 = *(const float4*)(wp);
                    float4 wb4 = *(const float4*)(wp + CP);
                    float4 da4 = *(const float4*)(wp + 2 * CP);
                    float4 db4 = *(const float4*)(wp + 3 * CP);
                    float wav[4] = {wa4.x, wa4.y, wa4.z, wa4.w};
                    float wbv[4] = {wb4.x, wb4.y, wb4.z, wb4.w};
                    float dav[4] = {da4.x, da4.y, da4.z, da4.w};
                    float dbv[4] = {db4.x, db4.y, db4.z, db4.w};
#pragma unroll
                    for (int i = 0; i < 4; ++i) {
                        aU[i][0] += wav[i] * x0; aU[i][1] += wav[i] * x1; aU[i][2] += wav[i] * x2;
                        aV[i][0] += wbv[i] * x0; aV[i][1] += wbv[i] * x1; aV[i][2] += wbv[i] * x2;
                        aDu[i][0] += dav[i] * x0; aDu[i][1] += dav[i] * x1; aDu[i][2] += dav[i] * x2;
                        aDv[i][0] += dbv[i] * x0; aDv[i][1] += dbv[i] * x1; aDv[i][2] += dbv[i] * x2;
                    }
                }

                size_t base = ((size_t)(bn0 + p) * Co + o0) * 3;
#pragma unroll
                for (int i = 0; i < 4; ++i) {
                    int o = o0 + i;
                    if (o < Co) {
                        size_t off = base + (size_t)i * 3;
                        U[off] = aU[i][0]; U[off + 1] = aU[i][1]; U[off + 2] = aU[i][2];
                        V[off] = aV[i][0]; V[off + 1] = aV[i][1]; V[off + 2] = aV[i][2];
                        UD[off] = aDu[i][0]; UD[off + 1] = aDu[i][1]; UD[off + 2] = aDu[i][2];
                        VD[off] = aDv[i][0]; VD[off + 1] = aDv[i][1]; VD[off + 2] = aDv[i][2];
                    }
                }
            }
        } else {
            // ------------ o-chunked pair-matmul (L4; R12-verified staging) ------------
            float* xs = sm + 4 * (C * OCH);   // after max chunk wts
            for (int t = tid; t < TILE * C3; t += 256) {
                int p = t / C3, cc = t % C3;
                xs[t] = Xp[(size_t)(bn0 + p) * rowStride + colOff + cc];
            }
            for (int o0c = 0; o0c < CoP; o0c += OCH) {
                int och = CoP - o0c; if (och > OCH) och = OCH;
                int CPc = C * och;
                float* wts = sm;
                __syncthreads();   // fences xs stage (1st iter) / prior compute reads
                for (int t = tid; t < 4 * CPc; t += 256) {
                    int mat = t / CPc; int r = t - mat * CPc;
                    int c = r / och; int oo = r - c * och;
                    int o = o0c + oo;
                    const float* srcw = (mat < 2) ? W : Dw;
                    int cc = (mat & 1) ? (C + c) : c;
                    wts[mat * CPc + c * och + oo] =
                        (o < Co) ? srcw[(size_t)o * 2 * C + cc] : 0.f;
                }
                __syncthreads();
                for (int t = tid; t < CPc; t += 256) {
                    wts[CPc + t] -= wts[t];
                    wts[3 * CPc + t] -= wts[2 * CPc + t];
                }
                __syncthreads();
                int GPP = och >> 2;
                int items = TILE * GPP;
                for (int e = tid; e < items; e += 256) {
                    int p = e / GPP, og = e - p * GPP;
                    int o0 = og * 4;
                    const float* xr = xs + p * C3;
                    float aU[4][3], aV[4][3], aDu[4][3], aDv[4][3];
#pragma unroll
                    for (int i = 0; i < 4; ++i)
#pragma unroll
                        for (int j = 0; j < 3; ++j) {
                            aU[i][j] = 0.f; aV[i][j] = 0.f; aDu[i][j] = 0.f; aDv[i][j] = 0.f;
                        }
                    for (int c = 0; c < C; ++c) {
                        float x0 = xr[c * 3], x1 = xr[c * 3 + 1], x2 = xr[c * 3 + 2];
                        const float* wp = wts + c * och + o0;
                        float4 wa4 = *(const float4*)(wp);
                        float4 wb4 = *(const float4*)(wp + CPc);
                        float4 da4 = *(const float4*)(wp + 2 * CPc);
                        float4 db4 = *(const float4*)(wp + 3 * CPc);
                        float wav[4] = {wa4.x, wa4.y, wa4.z, wa4.w};
                        float wbv[4] = {wb4.x, wb4.y, wb4.z, wb4.w};
                        float dav[4] = {da4.x, da4.y, da4.z, da4.w};
                        float dbv[4] = {db4.x, db4.y, db4.z, db4.w};
#pragma unroll
                        for (int i = 0; i < 4; ++i) {
                            aU[i][0] += wav[i] * x0; aU[i][1] += wav[i] * x1; aU[i][2] += wav[i] * x2;
                            aV[i][0] += wbv[i] * x0; aV[i][1] += wbv[i] * x1; aV[i][2] += wbv[i] * x2;
                            aDu[i][0] += dav[i] * x0; aDu[i][1] += dav[i] * x1; aDu[i][2] += dav[i] * x2;
                            aDv[i][0] += dbv[i] * x0; aDv[i][1] += dbv[i] * x1; aDv[i][2] += dbv[i] * x2;
                        }
                    }
                    size_t base = ((size_t)(bn0 + p) * Co + (o0c + o0)) * 3;
#pragma unroll
                    for (int i = 0; i < 4; ++i) {
                        int o = o0c + o0 + i;
                        if (o < Co) {
                            size_t off = base + (size_t)i * 3;
                            U[off] = aU[i][0]; U[off + 1] = aU[i][1]; U[off + 2] = aU[i][2];
                            V[off] = aV[i][0]; V[off + 1] = aV[i][1]; V[off + 2] = aV[i][2];
                            UD[off] = aDu[i][0]; UD[off + 1] = aDu[i][1]; UD[off + 2] = aDu[i][2];
                            VD[off] = aDv[i][0]; VD[off + 1] = aDv[i][1]; VD[off + 2] = aDv[i][2];
                        }
                    }
                }
            }
        }
        return;
    }

    // ---------------- knn body (R11 verbatim) ----------------
    int kb = (int)blockIdx.x - mmBlocks;
    int qbpb = N / qPerBlock;            // q-blocks per batch
    int b = kb / qbpb;
    int qbase = (kb - b * qbpb) * qPerBlock;
    int lane = tid & 63;
    int wave = tid >> 6;

    float* qf = sm;                      // 128*QT floats
    float* pdb = sm + 128 * QT;          // QT*1024 floats

    const float* Xb = Xn + (size_t)b * batchStride + sliceOff;
    const float* xxb = xx + (size_t)b * N;

    for (int q0 = qbase; q0 < qbase + qPerBlock; q0 += QT) {
        for (int t = tid; t < QT * D; t += 256) {
            int d = t >> 2, q = t & 3;
            qf[d * QT + q] = Xb[(size_t)d * N + (q0 + q)];
        }
        __syncthreads();

        float a0x = 0.f, a0y = 0.f, a0z = 0.f, a0w = 0.f;
        float a1x = 0.f, a1y = 0.f, a1z = 0.f, a1w = 0.f;
        float a2x = 0.f, a2y = 0.f, a2z = 0.f, a2w = 0.f;
        float a3x = 0.f, a3y = 0.f, a3z = 0.f, a3w = 0.f;

        const float* mbase = Xb + 4 * tid;
#pragma unroll 3
        for (int d = 0; d < D; ++d) {
            float4 xm = *(const float4*)(mbase + (size_t)d * N);
            float4 qv = *(const float4*)(qf + d * QT);
            a0x += qv.x * xm.x; a0y += qv.x * xm.y; a0z += qv.x * xm.z; a0w += qv.x * xm.w;
            a1x += qv.y * xm.x; a1y += qv.y * xm.y; a1z += qv.y * xm.z; a1w += qv.y * xm.w;
            a2x += qv.z * xm.x; a2y += qv.z * xm.y; a2z += qv.z * xm.z; a2w += qv.z * xm.w;
            a3x += qv.w * xm.x; a3y += qv.w * xm.y; a3z += qv.w * xm.z; a3w += qv.w * xm.w;
        }

        {
            float4 m2 = *(const float4*)(xxb + 4 * tid);
            float4 qn = *(const float4*)(xxb + q0);
            float4 v;
            v.x = 2.f * a0x - qn.x - m2.x; v.y = 2.f * a0y - qn.x - m2.y;
            v.z = 2.f * a0z - qn.x - m2.z; v.w = 2.f * a0w - qn.x - m2.w;
            *(float4*)(pdb + 0 * 1024 + 4 * tid) = v;
            v.x = 2.f * a1x - qn.y - m2.x; v.y = 2.f * a1y - qn.y - m2.y;
            v.z = 2.f * a1z - qn.y - m2.z; v.w = 2.f * a1w - qn.y - m2.w;
            *(float4*)(pdb + 1 * 1024 + 4 * tid) = v;
            v.x = 2.f * a2x - qn.z - m2.x; v.y = 2.f * a2y - qn.z - m2.y;
            v.z = 2.f * a2z - qn.z - m2.z; v.w = 2.f * a2w - qn.z - m2.w;
            *(float4*)(pdb + 2 * 1024 + 4 * tid) = v;
            v.x = 2.f * a3x - qn.w - m2.x; v.y = 2.f * a3y - qn.w - m2.y;
            v.z = 2.f * a3z - qn.w - m2.z; v.w = 2.f * a3w - qn.w - m2.w;
            *(float4*)(pdb + 3 * 1024 + 4 * tid) = v;
        }
        __syncthreads();

        unsigned long long key[16];
#pragma unroll
        for (int t = 0; t < 16; ++t) {
            unsigned u = __float_as_uint(pdb[wave * 1024 + t * 64 + lane]);
            u ^= (unsigned)((int)u >> 31) | 0x80000000u;
            unsigned lo = (unsigned)(1023 - t * 64) - (unsigned)lane;
            key[t] = ((unsigned long long)u << 32) | (unsigned long long)lo;
        }

#define CE(a, b)                                        \
        {                                               \
            unsigned long long ka = key[a], kb2 = key[b]; \
            bool sw = ka < kb2;                         \
            key[a] = sw ? kb2 : ka;                     \
            key[b] = sw ? ka : kb2;                     \
        }
        CE(0,1) CE(2,3) CE(4,5) CE(6,7) CE(8,9) CE(10,11) CE(12,13) CE(14,15)
        CE(0,2) CE(1,3) CE(4,6) CE(5,7) CE(8,10) CE(9,11) CE(12,14) CE(13,15)
        CE(1,2) CE(5,6) CE(9,10) CE(13,14)
        CE(0,4) CE(1,5) CE(2,6) CE(3,7) CE(8,12) CE(9,13) CE(10,14) CE(11,15)
        CE(2,4) CE(3,5) CE(10,12) CE(11,13)
        CE(1,2) CE(3,4) CE(5,6) CE(9,10) CE(11,12) CE(13,14)
        CE(0,8) CE(1,9) CE(2,10) CE(3,11) CE(4,12) CE(5,13) CE(6,14) CE(7,15)
        CE(4,8) CE(5,9) CE(6,10) CE(7,11)
        CE(2,4) CE(3,5) CE(6,8) CE(7,9) CE(10,12) CE(11,13)
        CE(1,2) CE(3,4) CE(5,6) CE(7,8) CE(9,10) CE(11,12) CE(13,14)
#undef CE

        __syncthreads();   // fence float reads vs u64 writes
        unsigned long long* kl = (unsigned long long*)(pdb + wave * 1024);
#pragma unroll
        for (int t = 8; t < 16; ++t) kl[(t - 8) * 64 + lane] = key[t];
        int nspill = 0;

        long outBase = ((long)b * N + q0 + wave) * KNN;
        for (int it = 0; it < KNN; ++it) {
            unsigned myh = (unsigned)(key[0] >> 32);
            unsigned mylo = (unsigned)(key[0] & 0xFFFFFFFFull);
            unsigned bh = myh;
#pragma unroll
            for (int off = 32; off >= 1; off >>= 1) {
                unsigned oh = __shfl_xor(bh, off, 64);
                if (oh > bh) bh = oh;
            }
            unsigned long long mask = __ballot(myh == bh);
            unsigned ml;
            if (__popcll(mask) == 1) {
                int src = (int)(__ffsll((long long)mask) - 1);
                ml = __shfl(mylo, src, 64);
            } else {
                unsigned cand = (myh == bh) ? mylo : 0u;
#pragma unroll
                for (int off = 32; off >= 1; off >>= 1) {
                    unsigned oc = __shfl_xor(cand, off, 64);
                    if (oc > cand) cand = oc;
                }
                ml = cand;
            }
            int bi = 1023 - (int)(ml & 1023u);
            if (lane == 0) idx[outBase + it] = bi;
            if ((bi & 63) == lane) {
                key[0] = key[1]; key[1] = key[2]; key[2] = key[3]; key[3] = key[4];
                key[4] = key[5]; key[5] = key[6]; key[6] = key[7];
                int sidx = nspill < 8 ? nspill : 7;
                unsigned long long nv = kl[sidx * 64 + lane];
                key[7] = (nspill < 8) ? nv : 0ull;
                nspill++;
            }
        }
        __syncthreads();   // protect qf/pd reuse across q-block passes
    }
}

// ---------------- BN stats stage A (deterministic, R5 order + LDS staging) ----------------
__global__ void k_stats_edge_det(const float* __restrict__ U, const float* __restrict__ V,
                                 const int* __restrict__ idx, float* __restrict__ partials,
                                 int N, int Co, int BN) {
    int o = blockIdx.x;
    int s = blockIdx.y;
    int tid = threadIdx.x;
    int P = BN / SSPLIT;      // == N == 1024
    int g0 = s * P;

    __shared__ float Ush[3072];   // N * 3 (channel-o vectors for batch s)
    __shared__ float r1[256], r2[256];

    for (int t = tid; t < P; t += 256) {
        F3 u3 = *(const F3*)(U + ((size_t)(g0 + t) * Co + o) * 3);
        Ush[t * 3 + 0] = u3.x;
        Ush[t * 3 + 1] = u3.y;
        Ush[t * 3 + 2] = u3.z;
    }
    __syncthreads();

    float s1 = 0.f, s2 = 0.f;
    for (int pl = tid; pl < P; pl += 256) {
        int g = g0 + pl;                       // flattened b*N+n
        F3 v3 = *(const F3*)(V + ((size_t)g * Co + o) * 3);
        float v0 = v3.x, v1 = v3.y, v2 = v3.z;
        const int* ip = idx + (size_t)g * KNN;
        for (int kk = 0; kk < KNN; ++kk) {
            const float* Ur = Ush + ip[kk] * 3;   // idx is batch-local
            float p0 = Ur[0] + v0;
            float p1 = Ur[1] + v1;
            float p2 = Ur[2] + v2;
            float nm = sqrtf(p0 * p0 + p1 * p1 + p2 * p2) + EPSV;
            s1 += nm;
            s2 += nm * nm;
        }
    }
    r1[tid] = s1; r2[tid] = s2;
    __syncthreads();
    for (int st = 128; st > 0; st >>= 1) {
        if (tid < st) { r1[tid] += r1[tid + st]; r2[tid] += r2[tid + st]; }
        __syncthreads();
    }
    if (tid == 0) {
        partials[(o * SSPLIT + s) * 2] = r1[0];
        partials[(o * SSPLIT + s) * 2 + 1] = r2[0];
    }
}

// ---------------- fused stage-B: BN + dir leaky + mean-pool + cat transpose + sqnorm ----
__global__ void k_final_fused(const float* __restrict__ U, const float* __restrict__ V,
                              const float* __restrict__ UD, const float* __restrict__ VD,
                              const int* __restrict__ idx, const float* __restrict__ partials,
                              const float* __restrict__ gamma, const float* __restrict__ beta,
                              float* __restrict__ catp, float* __restrict__ catn,
                              float* __restrict__ xx,
                              int N, int Co, int colOff, float cnt, int doSq) {
    int b = blockIdx.y;
    int n0 = blockIdx.x * TN;
    int tid = threadIdx.x;
    int CC = Co * 3;

    __shared__ float tile[TN * 255];    // TN x CC, CC <= 255
    __shared__ float muS[85], invS[85];

    for (int o = tid; o < Co; o += 256) {
        float s1 = 0.f, s2 = 0.f;
        for (int s = 0; s < SSPLIT; ++s) {
            s1 += partials[(o * SSPLIT + s) * 2];
            s2 += partials[(o * SSPLIT + s) * 2 + 1];
        }
        float mu = s1 / cnt;
        float var = s2 / cnt - mu * mu;
        muS[o] = mu;
        invS[o] = rsqrtf(var + 1e-5f);
    }
    __syncthreads();

    const float invk = 1.f / (float)KNN;
    int items = TN * Co;
    for (int e = tid; e < items; e += 256) {
        int nl = e / Co, o = e - nl * Co;
        int n = n0 + nl;
        float mu = muS[o], inv = invS[o];
        float gmm = gamma[o], bt = beta[o];

        size_t ctr = ((size_t)(b * N + n) * Co + o) * 3;
        F3 vc = *(const F3*)(V + ctr);
        F3 wc = *(const F3*)(VD + ctr);
        float v0 = vc.x, v1 = vc.y, v2 = vc.z;
        float w0 = wc.x, w1 = wc.y, w2 = wc.z;
        const int* ip = idx + ((size_t)b * N + n) * KNN;

        float a0 = 0.f, a1 = 0.f, a2 = 0.f;
        for (int kk = 0; kk < KNN; ++kk) {
            int m = ip[kk];
            size_t nb = ((size_t)(b * N + m) * Co + o) * 3;
            F3 un = *(const F3*)(U + nb);
            F3 dn = *(const F3*)(UD + nb);
            float p0 = un.x + v0;
            float p1 = un.y + v1;
            float p2 = un.z + v2;
            float nm = sqrtf(p0 * p0 + p1 * p1 + p2 * p2) + EPSV;
            float nbn = (nm - mu) * inv * gmm + bt;
            float sc = nbn / nm;
            p0 *= sc; p1 *= sc; p2 *= sc;
            float d0 = dn.x + w0;
            float d1 = dn.y + w1;
            float d2 = dn.z + w2;
            float dot = p0 * d0 + p1 * d1 + p2 * d2;
            if (dot >= 0.f) {
                a0 += p0; a1 += p1; a2 += p2;
            } else {
                float f = dot / (d0 * d0 + d1 * d1 + d2 * d2 + EPSV);
                a0 += NS * p0 + (1.f - NS) * (p0 - f * d0);
                a1 += NS * p1 + (1.f - NS) * (p1 - f * d1);
                a2 += NS * p2 + (1.f - NS) * (p2 - f * d2);
            }
        }
        tile[nl * CC + o * 3 + 0] = a0 * invk;
        tile[nl * CC + o * 3 + 1] = a1 * invk;
        tile[nl * CC + o * 3 + 2] = a2 * invk;
    }
    __syncthreads();

    for (int t = tid; t < TN * CC; t += 256) {
        int nl = t / CC, c = t - nl * CC;
        catp[(size_t)(b * N + n0 + nl) * CROW + colOff + c] = tile[nl * CC + c];
    }
    for (int t = tid; t < TN * CC; t += 256) {
        int c = t >> 3, nl = t & (TN - 1);   // TN == 8
        catn[(size_t)b * CROW * N + (size_t)(colOff + c) * N + n0 + nl] = tile[nl * CC + c];
    }
    if (doSq && tid < TN) {
        const float* row = tile + tid * CC;
        float s = 0.f;
        for (int c = 0; c < CC; ++c) {
            float v = row[c];
            s += v * v;
        }
        xx[(size_t)b * N + n0 + tid] = s;
    }
}

// ---------------- plain matmul (layer 5, n-major): U = W*x, j-fused + 2-n tile ----------
__global__ void k_matmul_plain(const float* __restrict__ X, const float* __restrict__ W,
                               const float* __restrict__ Dw,
                               float* __restrict__ U, float* __restrict__ Ud,
                               int N, int Cin, int Cout, long batchStride, long sliceOff) {
    int ot = blockIdx.y;
    int b = blockIdx.z;
    int tid = threadIdx.x;
    int n = blockIdx.x * 512 + 2 * tid;

    const float* Wp; float* Up; int CoutE; int o0;
    if (ot == (int)gridDim.y - 1) {   // Dw path
        Wp = Dw; Up = Ud; CoutE = 1; o0 = 0;
    } else {
        Wp = W; Up = U; CoutE = Cout; o0 = ot * OT;
    }

    __shared__ __align__(16) float wsm[OT][176];
    for (int t = tid; t < OT * Cin; t += 256) {
        int oo = t / Cin, c = t % Cin;
        int o = o0 + oo;
        wsm[oo][c] = (o < CoutE) ? Wp[(size_t)o * Cin + c] : 0.f;
    }
    __syncthreads();

    const float* Xp = X + (size_t)b * batchStride + sliceOff + n;
    float au[OT][3][2];
#pragma unroll
    for (int oo = 0; oo < OT; ++oo)
#pragma unroll
        for (int j = 0; j < 3; ++j) {
            au[oo][j][0] = 0.f; au[oo][j][1] = 0.f;
        }

    int c = 0;
    for (; c + 4 <= Cin; c += 4) {
        float2 xv[4][3];
#pragma unroll
        for (int cc = 0; cc < 4; ++cc)
#pragma unroll
            for (int j = 0; j < 3; ++j)
                xv[cc][j] = *(const float2*)(Xp + ((size_t)(c + cc) * 3 + j) * N);
#pragma unroll
        for (int oo = 0; oo < OT; ++oo) {
            float4 w4 = *(const float4*)&wsm[oo][c];
            float wv[4] = {w4.x, w4.y, w4.z, w4.w};
#pragma unroll
            for (int j = 0; j < 3; ++j) {
#pragma unroll
                for (int cc = 0; cc < 4; ++cc) {
                    au[oo][j][0] += wv[cc] * xv[cc][j].x;
                    au[oo][j][1] += wv[cc] * xv[cc][j].y;
                }
            }
        }
    }
    for (; c < Cin; ++c) {
        float2 xv[3];
#pragma unroll
        for (int j = 0; j < 3; ++j)
            xv[j] = *(const float2*)(Xp + ((size_t)c * 3 + j) * N);
#pragma unroll
        for (int oo = 0; oo < OT; ++oo) {
            float wv = wsm[oo][c];
#pragma unroll
            for (int j = 0; j < 3; ++j) {
                au[oo][j][0] += wv * xv[j].x;
                au[oo][j][1] += wv * xv[j].y;
            }
        }
    }
#pragma unroll
    for (int oo = 0; oo < OT; ++oo) {
        int o = o0 + oo;
        if (o < CoutE) {
#pragma unroll
            for (int j = 0; j < 3; ++j) {
                float2 st; st.x = au[oo][j][0]; st.y = au[oo][j][1];
                *(float2*)&Up[(((size_t)b * CoutE + o) * 3 + j) * N + n] = st;
            }
        }
    }
}

// ---------------- layer-5 stats (deterministic): one block per channel ----------------
__global__ void k_stats_plain_det(const float* __restrict__ U, float* __restrict__ mv,
                                  int N, int Cout, int BN, float cnt) {
    int o = blockIdx.x;
    int tid = threadIdx.x;
    float s1 = 0.f, s2 = 0.f;
    for (int g = tid; g < BN; g += 256) {
        int b = g / N, n = g % N;
        const float* Ub = U + (((size_t)b * Cout + o) * 3) * N;
        float p0 = Ub[n], p1 = Ub[(size_t)N + n], p2 = Ub[(size_t)2 * N + n];
        float nm = sqrtf(p0 * p0 + p1 * p1 + p2 * p2) + EPSV;
        s1 += nm;
        s2 += nm * nm;
    }
    __shared__ float r1[256], r2[256];
    r1[tid] = s1; r2[tid] = s2;
    __syncthreads();
    for (int st = 128; st > 0; st >>= 1) {
        if (tid < st) { r1[tid] += r1[tid + st]; r2[tid] += r2[tid + st]; }
        __syncthreads();
    }
    if (tid == 0) {
        float mu = r1[0] / cnt;
        float var = r2[0] / cnt - mu * mu;
        mv[2 * o] = mu;
        mv[2 * o + 1] = rsqrtf(var + 1e-5f);
    }
}

// ---------------- layer-5 final: BN + dir leaky (1 dir channel) -> d_out ----------------
__global__ void k_final_plain(const float* __restrict__ U, const float* __restrict__ Dv,
                              const float* __restrict__ mv,
                              const float* __restrict__ gamma, const float* __restrict__ beta,
                              float* __restrict__ out, int N, int Cout) {
    int b = blockIdx.z, o = blockIdx.y, tid = threadIdx.x;
    int n = blockIdx.x * 256 + tid;
    float mu = mv[2 * o];
    float inv = mv[2 * o + 1];
    float g = gamma[o], bt = beta[o];

    const float* Ub = U + (((size_t)b * Cout + o) * 3) * N;
    float p0 = Ub[n], p1 = Ub[(size_t)N + n], p2 = Ub[(size_t)2 * N + n];
    float nm = sqrtf(p0 * p0 + p1 * p1 + p2 * p2) + EPSV;
    float nbn = (nm - mu) * inv * g + bt;
    float sc = nbn / nm;
    p0 *= sc; p1 *= sc; p2 *= sc;

    float d0 = Dv[((size_t)b * 3 + 0) * N + n];
    float d1 = Dv[((size_t)b * 3 + 1) * N + n];
    float d2 = Dv[((size_t)b * 3 + 2) * N + n];
    float dot = p0 * d0 + p1 * d1 + p2 * d2;
    float o0, o1, o2;
    if (dot >= 0.f) {
        o0 = p0; o1 = p1; o2 = p2;
    } else {
        float f = dot / (d0 * d0 + d1 * d1 + d2 * d2 + EPSV);
        o0 = NS * p0 + (1.f - NS) * (p0 - f * d0);
        o1 = NS * p1 + (1.f - NS) * (p1 - f * d1);
        o2 = NS * p2 + (1.f - NS) * (p2 - f * d2);
    }
    size_t ob = (((size_t)b * Cout + o) * 3) * N + n;
    out[ob] = o0;
    out[ob + (size_t)N] = o1;
    out[ob + (size_t)2 * N] = o2;
}

extern "C" void kernel_launch(void* const* d_in, const int* in_sizes, int n_in,
                              void* d_out, int out_size, void* d_ws, size_t ws_size,
                              hipStream_t stream) {
    (void)in_sizes; (void)n_in; (void)out_size; (void)ws_size;
    const int B = 8, N = 1024;

    const float* x = (const float*)d_in[0];
    const float* W[5]; const float* Dw[5]; const float* G[5]; const float* Bt[5];
    for (int l = 0; l < 5; ++l) {
        W[l]  = (const float*)d_in[1 + 4 * l];
        Dw[l] = (const float*)d_in[2 + 4 * l];
        G[l]  = (const float*)d_in[3 + 4 * l];
        Bt[l] = (const float*)d_in[4 + 4 * l];
    }

    float* ws = (float*)d_ws;
    size_t off = 0;
    float* xt = ws + off;     off += (size_t)B * 3 * N;
    int* idx = (int*)(ws + off); off += (size_t)B * N * KNN;
    float* catp = ws + off;   off += (size_t)B * N * CROW;
    float* catn = ws + off;   off += (size_t)B * N * CROW;
    float* Up = ws + off;     off += (size_t)B * N * 85 * 3;
    float* Vp = ws + off;     off += (size_t)B * N * 85 * 3;
    float* UDp = ws + off;    off += (size_t)B * N * 85 * 3;
    float* VDp = ws + off;    off += (size_t)B * N * 85 * 3;
    float* U5 = ws + off;     off += (size_t)B * 341 * 3 * N;
    float* d5buf = ws + off;  off += (size_t)B * 3 * N;
    float* xx = ws + off;     off += (size_t)B * N;
    float* partials = ws + off; off += (size_t)341 * SSPLIT * 2;
    float* mv = ws + off;     off += 2 * 341;

    k_transpose<<<(B * N + 255) / 256, 256, 0, stream>>>(x, xt, xx, B, N);

    const int Cin_[4]  = {1, 21, 21, 42};
    const int Cout_[4] = {21, 21, 42, 85};
    const int inOff_[4] = {-1, 0, 21, 42};
    const int outOff_[4] = {0, 21, 42, 84};
    const int Tile_[4] = {32, 32, 16, 8};   // L3 TILE=16 fits whole; L4 TILE=8 chunked

    const int BN = B * N;
    const size_t KNN_LDS = (size_t)(128 * QT + QT * 1024) * sizeof(float);   // 18432

    for (int l = 0; l < 4; ++l) {
        int C = Cin_[l], Co = Cout_[l];
        int D = C * 3;
        int CoP = (Co + 3) & ~3;
        int TILE = Tile_[l];
        int chunked = (l == 3) ? 1 : 0;

        const float* Xn; long bs, so;
        if (inOff_[l] < 0) { Xn = xt; bs = (long)3 * N; so = 0; }
        else { Xn = catn; bs = (long)CROW * N; so = (long)inOff_[l] * 3 * N; }

        const float* Xp; int rs, co;
        if (inOff_[l] < 0) { Xp = x; rs = 3; co = 0; }
        else { Xp = catp; rs = CROW; co = inOff_[l] * 3; }

        // all 4 layers fused: mm blocks first (overlap in knn's shadow), knn 8 q/block
        int mmB = BN / TILE;
        int knnB = BN / 8;
        size_t mmNeed = chunked
            ? (size_t)(4 * C * OCH + TILE * C * 3) * sizeof(float)
            : (size_t)(4 * C * CoP + TILE * C * 3) * sizeof(float);
        size_t smemB = mmNeed > KNN_LDS ? mmNeed : KNN_LDS;
        k_knn_mm<<<mmB + knnB, 256, smemB, stream>>>(
            Xn, xx, idx, N, D, bs, so, 8,
            Xp, W[l], Dw[l], Up, Vp, UDp, VDp, C, Co, CoP, TILE, rs, co, mmB, chunked);

        dim3 gst(Co, SSPLIT);
        k_stats_edge_det<<<gst, 256, 0, stream>>>(Up, Vp, idx, partials, N, Co, BN);

        int doSq = (l < 3) ? 1 : 0;
        dim3 gf(N / TN, B);
        k_final_fused<<<gf, 256, 0, stream>>>(
            Up, Vp, UDp, VDp, idx, partials, G[l], Bt[l],
            catp, catn, xx, N, Co, outOff_[l] * 3,
            (float)((size_t)BN * KNN), doSq);
    }

    // layer 5 (reads catn n-major); W and Dw matmuls merged into one launch
    {
        long bs = (long)CROW * N, so = 0;
        dim3 gm5(N / 512, (341 + OT - 1) / OT + 1, B);   // +1: Dw tile
        k_matmul_plain<<<gm5, 256, 0, stream>>>(catn, W[4], Dw[4], U5, d5buf,
                                                N, 169, 341, bs, so);
        k_stats_plain_det<<<341, 256, 0, stream>>>(U5, mv, N, 341, BN, (float)BN);
        dim3 gs5(N / 256, 341, B);
        k_final_plain<<<gs5, 256, 0, stream>>>(U5, d5buf, mv, G[4], Bt[4],
                                               (float*)d_out, N, 341);
    }
}

// Round 14
// 652.407 us; speedup vs baseline: 4.3910x; 1.0311x over previous
//
#include <hip/hip_runtime.h>
#include <math.h>

#define KNN 20
#define NS 0.2f
#define EPSV 1e-6f
#define QT 4
#define OT 8
#define TN 8       // n-tile of k_final_fused
#define CROW 507   // 169*3, cat row stride (floats)
#define SSPLIT 8   // stats splits (== B; split s covers batch s exactly)

struct F3 { float x, y, z; };   // 12-byte vector load (global_load_dwordx3)

extern __shared__ __align__(16) float smem[];

// ---------------- transpose (B,N,3) -> (B,3,N) + fused sqnorm (layer-1) ----------------
__global__ void k_transpose(const float* __restrict__ x, float* __restrict__ xt,
                            float* __restrict__ xx, int B, int N) {
    int i = blockIdx.x * blockDim.x + threadIdx.x;
    if (i >= B * N) return;
    int b = i / N, n = i % N;
    const float* src = x + (size_t)(b * N + n) * 3;
    float* dst = xt + (size_t)b * 3 * N + n;
    float s0 = src[0], s1 = src[1], s2 = src[2];
    dst[0] = s0;
    dst[(size_t)N] = s1;
    dst[(size_t)2 * N] = s2;
    float s = 0.f;
    s += s0 * s0;
    s += s1 * s1;
    s += s2 * s2;
    xx[i] = s;
}

// ---------------- fused knn + pair-matmul launch (R11, best measured) ----------------
// Blocks [0, mmBlocks) run the pair-matmul body; blocks [mmBlocks, ...) run
// knn, each handling qPerBlock queries (qPerBlock/QT sequential passes).
// knn fills ~half the residency slots (1024 blocks when qPerBlock=8), so the
// mm blocks execute concurrently in knn's shadow instead of serializing.
__global__ void k_knn_mm(// knn args
                         const float* __restrict__ Xn, const float* __restrict__ xx,
                         int* __restrict__ idx, int N, int D,
                         long batchStride, long sliceOff, int qPerBlock,
                         // mm args
                         const float* __restrict__ Xp, const float* __restrict__ W,
                         const float* __restrict__ Dw,
                         float* __restrict__ U, float* __restrict__ V,
                         float* __restrict__ UD, float* __restrict__ VD,
                         int C, int Co, int CoP, int TILE,
                         int rowStride, int colOff, int mmBlocks) {
    float* sm = smem;
    int tid = threadIdx.x;

    if ((int)blockIdx.x < mmBlocks) {
        // ---------------- pair-matmul body (verbatim math) ----------------
        const int CP = C * CoP;
        float* wts = sm;            // 4*CP
        float* xs = sm + 4 * CP;    // TILE * C * 3
        int bn0 = blockIdx.x * TILE;
        int C3 = C * 3;

        int npad = CoP - Co;
        if (npad) {
            for (int t = tid; t < 4 * C * npad; t += 256) {
                int q = t / npad, oo = Co + t % npad;
                int mat = q / C, c = q % C;
                wts[mat * CP + c * CoP + oo] = 0.f;
            }
        }
        int twoCC = 2 * C * Co;
        for (int t = tid; t < twoCC; t += 256) {
            int o = t / (2 * C), c = t % (2 * C);
            float w = W[t], dw = Dw[t];
            if (c < C) {
                wts[c * CoP + o] = w;
                wts[2 * CP + c * CoP + o] = dw;
            } else {
                wts[CP + (c - C) * CoP + o] = w;
                wts[3 * CP + (c - C) * CoP + o] = dw;
            }
        }
        for (int t = tid; t < TILE * C3; t += 256) {
            int p = t / C3, cc = t % C3;
            xs[t] = Xp[(size_t)(bn0 + p) * rowStride + colOff + cc];
        }
        __syncthreads();
        for (int t = tid; t < CP; t += 256) {
            wts[CP + t] -= wts[t];
            wts[3 * CP + t] -= wts[2 * CP + t];
        }
        __syncthreads();

        int GPP = CoP >> 2;
        int items = TILE * GPP;
        for (int e = tid; e < items; e += 256) {
            int p = e / GPP, og = e - p * GPP;
            int o0 = og * 4;
            const float* xr = xs + p * C3;

            float aU[4][3], aV[4][3], aDu[4][3], aDv[4][3];
#pragma unroll
            for (int i = 0; i < 4; ++i)
#pragma unroll
                for (int j = 0; j < 3; ++j) {
                    aU[i][j] = 0.f; aV[i][j] = 0.f; aDu[i][j] = 0.f; aDv[i][j] = 0.f;
                }

            for (int c = 0; c < C; ++c) {
                float x0 = xr[c * 3], x1 = xr[c * 3 + 1], x2 = xr[c * 3 + 2];
                const float* wp = wts + c * CoP + o0;
                float4 wa4 = *(const float4*)(wp);
                float4 wb4 = *(const float4*)(wp + CP);
                float4 da4 = *(const float4*)(wp + 2 * CP);
                float4 db4 = *(const float4*)(wp + 3 * CP);
                float wav[4] = {wa4.x, wa4.y, wa4.z, wa4.w};
                float wbv[4] = {wb4.x, wb4.y, wb4.z, wb4.w};
                float dav[4] = {da4.x, da4.y, da4.z, da4.w};
                float dbv[4] = {db4.x, db4.y, db4.z, db4.w};
#pragma unroll
                for (int i = 0; i < 4; ++i) {
                    aU[i][0] += wav[i] * x0; aU[i][1] += wav[i] * x1; aU[i][2] += wav[i] * x2;
                    aV[i][0] += wbv[i] * x0; aV[i][1] += wbv[i] * x1; aV[i][2] += wbv[i] * x2;
                    aDu[i][0] += dav[i] * x0; aDu[i][1] += dav[i] * x1; aDu[i][2] += dav[i] * x2;
                    aDv[i][0] += dbv[i] * x0; aDv[i][1] += dbv[i] * x1; aDv[i][2] += dbv[i] * x2;
                }
            }

            size_t base = ((size_t)(bn0 + p) * Co + o0) * 3;
#pragma unroll
            for (int i = 0; i < 4; ++i) {
                int o = o0 + i;
                if (o < Co) {
                    size_t off = base + (size_t)i * 3;
                    U[off] = aU[i][0]; U[off + 1] = aU[i][1]; U[off + 2] = aU[i][2];
                    V[off] = aV[i][0]; V[off + 1] = aV[i][1]; V[off + 2] = aV[i][2];
                    UD[off] = aDu[i][0]; UD[off + 1] = aDu[i][1]; UD[off + 2] = aDu[i][2];
                    VD[off] = aDv[i][0]; VD[off + 1] = aDv[i][1]; VD[off + 2] = aDv[i][2];
                }
            }
        }
        return;
    }

    // ---------------- knn body (R10 selection, verbatim math) ----------------
    int kb = (int)blockIdx.x - mmBlocks;
    int qbpb = N / qPerBlock;            // q-blocks per batch
    int b = kb / qbpb;
    int qbase = (kb - b * qbpb) * qPerBlock;
    int lane = tid & 63;
    int wave = tid >> 6;

    float* qf = sm;                      // 128*QT floats
    float* pdb = sm + 128 * QT;          // QT*1024 floats

    const float* Xb = Xn + (size_t)b * batchStride + sliceOff;
    const float* xxb = xx + (size_t)b * N;

    for (int q0 = qbase; q0 < qbase + qPerBlock; q0 += QT) {
        for (int t = tid; t < QT * D; t += 256) {
            int d = t >> 2, q = t & 3;
            qf[d * QT + q] = Xb[(size_t)d * N + (q0 + q)];
        }
        __syncthreads();

        float a0x = 0.f, a0y = 0.f, a0z = 0.f, a0w = 0.f;
        float a1x = 0.f, a1y = 0.f, a1z = 0.f, a1w = 0.f;
        float a2x = 0.f, a2y = 0.f, a2z = 0.f, a2w = 0.f;
        float a3x = 0.f, a3y = 0.f, a3z = 0.f, a3w = 0.f;

        const float* mbase = Xb + 4 * tid;
#pragma unroll 3
        for (int d = 0; d < D; ++d) {
            float4 xm = *(const float4*)(mbase + (size_t)d * N);
            float4 qv = *(const float4*)(qf + d * QT);
            a0x += qv.x * xm.x; a0y += qv.x * xm.y; a0z += qv.x * xm.z; a0w += qv.x * xm.w;
            a1x += qv.y * xm.x; a1y += qv.y * xm.y; a1z += qv.y * xm.z; a1w += qv.y * xm.w;
            a2x += qv.z * xm.x; a2y += qv.z * xm.y; a2z += qv.z * xm.z; a2w += qv.z * xm.w;
            a3x += qv.w * xm.x; a3y += qv.w * xm.y; a3z += qv.w * xm.z; a3w += qv.w * xm.w;
        }

        {
            float4 m2 = *(const float4*)(xxb + 4 * tid);
            float4 qn = *(const float4*)(xxb + q0);
            float4 v;
            v.x = 2.f * a0x - qn.x - m2.x; v.y = 2.f * a0y - qn.x - m2.y;
            v.z = 2.f * a0z - qn.x - m2.z; v.w = 2.f * a0w - qn.x - m2.w;
            *(float4*)(pdb + 0 * 1024 + 4 * tid) = v;
            v.x = 2.f * a1x - qn.y - m2.x; v.y = 2.f * a1y - qn.y - m2.y;
            v.z = 2.f * a1z - qn.y - m2.z; v.w = 2.f * a1w - qn.y - m2.w;
            *(float4*)(pdb + 1 * 1024 + 4 * tid) = v;
            v.x = 2.f * a2x - qn.z - m2.x; v.y = 2.f * a2y - qn.z - m2.y;
            v.z = 2.f * a2z - qn.z - m2.z; v.w = 2.f * a2w - qn.z - m2.w;
            *(float4*)(pdb + 2 * 1024 + 4 * tid) = v;
            v.x = 2.f * a3x - qn.w - m2.x; v.y = 2.f * a3y - qn.w - m2.y;
            v.z = 2.f * a3z - qn.w - m2.z; v.w = 2.f * a3w - qn.w - m2.w;
            *(float4*)(pdb + 3 * 1024 + 4 * tid) = v;
        }
        __syncthreads();

        // ---- sortable keys: hi = orderable(float bits), lo = 1023 - idx ----
        unsigned long long key[16];
#pragma unroll
        for (int t = 0; t < 16; ++t) {
            unsigned u = __float_as_uint(pdb[wave * 1024 + t * 64 + lane]);
            u ^= (unsigned)((int)u >> 31) | 0x80000000u;
            unsigned lo = (unsigned)(1023 - t * 64) - (unsigned)lane;
            key[t] = ((unsigned long long)u << 32) | (unsigned long long)lo;
        }

        // ---- explicit Batcher odd-even mergesort n=16 (descending) ----
#define CE(a, b)                                        \
        {                                               \
            unsigned long long ka = key[a], kb2 = key[b]; \
            bool sw = ka < kb2;                         \
            key[a] = sw ? kb2 : ka;                     \
            key[b] = sw ? ka : kb2;                     \
        }
        CE(0,1) CE(2,3) CE(4,5) CE(6,7) CE(8,9) CE(10,11) CE(12,13) CE(14,15)
        CE(0,2) CE(1,3) CE(4,6) CE(5,7) CE(8,10) CE(9,11) CE(12,14) CE(13,15)
        CE(1,2) CE(5,6) CE(9,10) CE(13,14)
        CE(0,4) CE(1,5) CE(2,6) CE(3,7) CE(8,12) CE(9,13) CE(10,14) CE(11,15)
        CE(2,4) CE(3,5) CE(10,12) CE(11,13)
        CE(1,2) CE(3,4) CE(5,6) CE(9,10) CE(11,12) CE(13,14)
        CE(0,8) CE(1,9) CE(2,10) CE(3,11) CE(4,12) CE(5,13) CE(6,14) CE(7,15)
        CE(4,8) CE(5,9) CE(6,10) CE(7,11)
        CE(2,4) CE(3,5) CE(6,8) CE(7,9) CE(10,12) CE(11,13)
        CE(1,2) CE(3,4) CE(5,6) CE(7,8) CE(9,10) CE(11,12) CE(13,14)
#undef CE

        // ---- spill keys 8..15 to pdb[wave]'s row (dead after key build) ----
        __syncthreads();   // fence float reads vs u64 writes
        unsigned long long* kl = (unsigned long long*)(pdb + wave * 1024);
#pragma unroll
        for (int t = 8; t < 16; ++t) kl[(t - 8) * 64 + lane] = key[t];
        int nspill = 0;

        // ---- 20 extractions: hi butterfly + ballot resolve + owner pop ----
        long outBase = ((long)b * N + q0 + wave) * KNN;
        for (int it = 0; it < KNN; ++it) {
            unsigned myh = (unsigned)(key[0] >> 32);
            unsigned mylo = (unsigned)(key[0] & 0xFFFFFFFFull);
            unsigned bh = myh;
#pragma unroll
            for (int off = 32; off >= 1; off >>= 1) {
                unsigned oh = __shfl_xor(bh, off, 64);
                if (oh > bh) bh = oh;
            }
            unsigned long long mask = __ballot(myh == bh);
            unsigned ml;
            if (__popcll(mask) == 1) {
                int src = (int)(__ffsll((long long)mask) - 1);
                ml = __shfl(mylo, src, 64);
            } else {
                unsigned cand = (myh == bh) ? mylo : 0u;
#pragma unroll
                for (int off = 32; off >= 1; off >>= 1) {
                    unsigned oc = __shfl_xor(cand, off, 64);
                    if (oc > cand) cand = oc;
                }
                ml = cand;
            }
            int bi = 1023 - (int)(ml & 1023u);
            if (lane == 0) idx[outBase + it] = bi;
            if ((bi & 63) == lane) {
                key[0] = key[1]; key[1] = key[2]; key[2] = key[3]; key[3] = key[4];
                key[4] = key[5]; key[5] = key[6]; key[6] = key[7];
                int sidx = nspill < 8 ? nspill : 7;
                unsigned long long nv = kl[sidx * 64 + lane];
                key[7] = (nspill < 8) ? nv : 0ull;
                nspill++;
            }
        }
        __syncthreads();   // protect qf/pd reuse across q-block passes
    }
}

// ---------------- LDS-staged point-major pair matmul (layer 4 only: 62KB LDS) ----------
__global__ void k_matmul_pair_lds(const float* __restrict__ X, const float* __restrict__ W,
                                  const float* __restrict__ Dw,
                                  float* __restrict__ U, float* __restrict__ V,
                                  float* __restrict__ UD, float* __restrict__ VD,
                                  int C, int Co, int CoP, int TILE,
                                  int rowStride, int colOff) {
    const int CP = C * CoP;
    float* wts = smem;
    float* xs = smem + 4 * CP;

    int tid = threadIdx.x;
    int bn0 = blockIdx.x * TILE;
    int C3 = C * 3;

    int npad = CoP - Co;
    if (npad) {
        for (int t = tid; t < 4 * C * npad; t += 256) {
            int q = t / npad, oo = Co + t % npad;
            int mat = q / C, c = q % C;
            wts[mat * CP + c * CoP + oo] = 0.f;
        }
    }
    int twoCC = 2 * C * Co;
    for (int t = tid; t < twoCC; t += 256) {
        int o = t / (2 * C), c = t % (2 * C);
        float w = W[t], dw = Dw[t];
        if (c < C) {
            wts[c * CoP + o] = w;
            wts[2 * CP + c * CoP + o] = dw;
        } else {
            wts[CP + (c - C) * CoP + o] = w;
            wts[3 * CP + (c - C) * CoP + o] = dw;
        }
    }
    for (int t = tid; t < TILE * C3; t += 256) {
        int p = t / C3, cc = t % C3;
        xs[t] = X[(size_t)(bn0 + p) * rowStride + colOff + cc];
    }
    __syncthreads();
    for (int t = tid; t < CP; t += 256) {
        wts[CP + t] -= wts[t];
        wts[3 * CP + t] -= wts[2 * CP + t];
    }
    __syncthreads();

    int GPP = CoP >> 2;
    int items = TILE * GPP;
    for (int e = tid; e < items; e += 256) {
        int p = e / GPP, og = e - p * GPP;
        int o0 = og * 4;
        const float* xr = xs + p * C3;

        float aU[4][3], aV[4][3], aDu[4][3], aDv[4][3];
#pragma unroll
        for (int i = 0; i < 4; ++i)
#pragma unroll
            for (int j = 0; j < 3; ++j) {
                aU[i][j] = 0.f; aV[i][j] = 0.f; aDu[i][j] = 0.f; aDv[i][j] = 0.f;
            }

        for (int c = 0; c < C; ++c) {
            float x0 = xr[c * 3], x1 = xr[c * 3 + 1], x2 = xr[c * 3 + 2];
            const float* wp = wts + c * CoP + o0;
            float4 wa4 = *(const float4*)(wp);
            float4 wb4 = *(const float4*)(wp + CP);
            float4 da4 = *(const float4*)(wp + 2 * CP);
            float4 db4 = *(const float4*)(wp + 3 * CP);
            float wav[4] = {wa4.x, wa4.y, wa4.z, wa4.w};
            float wbv[4] = {wb4.x, wb4.y, wb4.z, wb4.w};
            float dav[4] = {da4.x, da4.y, da4.z, da4.w};
            float dbv[4] = {db4.x, db4.y, db4.z, db4.w};
#pragma unroll
            for (int i = 0; i < 4; ++i) {
                aU[i][0] += wav[i] * x0; aU[i][1] += wav[i] * x1; aU[i][2] += wav[i] * x2;
                aV[i][0] += wbv[i] * x0; aV[i][1] += wbv[i] * x1; aV[i][2] += wbv[i] * x2;
                aDu[i][0] += dav[i] * x0; aDu[i][1] += dav[i] * x1; aDu[i][2] += dav[i] * x2;
                aDv[i][0] += dbv[i] * x0; aDv[i][1] += dbv[i] * x1; aDv[i][2] += dbv[i] * x2;
            }
        }

        size_t base = ((size_t)(bn0 + p) * Co + o0) * 3;
#pragma unroll
        for (int i = 0; i < 4; ++i) {
            int o = o0 + i;
            if (o < Co) {
                size_t off = base + (size_t)i * 3;
                U[off] = aU[i][0]; U[off + 1] = aU[i][1]; U[off + 2] = aU[i][2];
                V[off] = aV[i][0]; V[off + 1] = aV[i][1]; V[off + 2] = aV[i][2];
                UD[off] = aDu[i][0]; UD[off + 1] = aDu[i][1]; UD[off + 2] = aDu[i][2];
                VD[off] = aDv[i][0]; VD[off + 1] = aDv[i][1]; VD[off + 2] = aDv[i][2];
            }
        }
    }
}

// ---------------- BN stats stage A (deterministic, R5 order + LDS staging) ----------------
__global__ void k_stats_edge_det(const float* __restrict__ U, const float* __restrict__ V,
                                 const int* __restrict__ idx, float* __restrict__ partials,
                                 int N, int Co, int BN) {
    int o = blockIdx.x;
    int s = blockIdx.y;
    int tid = threadIdx.x;
    int P = BN / SSPLIT;      // == N == 1024
    int g0 = s * P;

    __shared__ float Ush[3072];   // N * 3 (channel-o vectors for batch s)
    __shared__ float r1[256], r2[256];

    for (int t = tid; t < P; t += 256) {
        F3 u3 = *(const F3*)(U + ((size_t)(g0 + t) * Co + o) * 3);
        Ush[t * 3 + 0] = u3.x;
        Ush[t * 3 + 1] = u3.y;
        Ush[t * 3 + 2] = u3.z;
    }
    __syncthreads();

    float s1 = 0.f, s2 = 0.f;
    for (int pl = tid; pl < P; pl += 256) {
        int g = g0 + pl;                       // flattened b*N+n
        F3 v3 = *(const F3*)(V + ((size_t)g * Co + o) * 3);
        float v0 = v3.x, v1 = v3.y, v2 = v3.z;
        const int* ip = idx + (size_t)g * KNN;
        for (int kk = 0; kk < KNN; ++kk) {
            const float* Ur = Ush + ip[kk] * 3;   // idx is batch-local
            float p0 = Ur[0] + v0;
            float p1 = Ur[1] + v1;
            float p2 = Ur[2] + v2;
            float nm = sqrtf(p0 * p0 + p1 * p1 + p2 * p2) + EPSV;
            s1 += nm;
            s2 += nm * nm;
        }
    }
    r1[tid] = s1; r2[tid] = s2;
    __syncthreads();
    for (int st = 128; st > 0; st >>= 1) {
        if (tid < st) { r1[tid] += r1[tid + st]; r2[tid] += r2[tid + st]; }
        __syncthreads();
    }
    if (tid == 0) {
        partials[(o * SSPLIT + s) * 2] = r1[0];
        partials[(o * SSPLIT + s) * 2 + 1] = r2[0];
    }
}

// ---------------- fused stage-B: BN + dir leaky + mean-pool + cat transpose + sqnorm ----
__global__ void k_final_fused(const float* __restrict__ U, const float* __restrict__ V,
                              const float* __restrict__ UD, const float* __restrict__ VD,
                              const int* __restrict__ idx, const float* __restrict__ partials,
                              const float* __restrict__ gamma, const float* __restrict__ beta,
                              float* __restrict__ catp, float* __restrict__ catn,
                              float* __restrict__ xx,
                              int N, int Co, int colOff, float cnt, int doSq) {
    int b = blockIdx.y;
    int n0 = blockIdx.x * TN;
    int tid = threadIdx.x;
    int CC = Co * 3;

    __shared__ float tile[TN * 255];    // TN x CC, CC <= 255
    __shared__ float muS[85], invS[85];

    for (int o = tid; o < Co; o += 256) {
        float s1 = 0.f, s2 = 0.f;
        for (int s = 0; s < SSPLIT; ++s) {
            s1 += partials[(o * SSPLIT + s) * 2];
            s2 += partials[(o * SSPLIT + s) * 2 + 1];
        }
        float mu = s1 / cnt;
        float var = s2 / cnt - mu * mu;
        muS[o] = mu;
        invS[o] = rsqrtf(var + 1e-5f);
    }
    __syncthreads();

    const float invk = 1.f / (float)KNN;
    int items = TN * Co;
    for (int e = tid; e < items; e += 256) {
        int nl = e / Co, o = e - nl * Co;
        int n = n0 + nl;
        float mu = muS[o], inv = invS[o];
        float gmm = gamma[o], bt = beta[o];

        size_t ctr = ((size_t)(b * N + n) * Co + o) * 3;
        F3 vc = *(const F3*)(V + ctr);
        F3 wc = *(const F3*)(VD + ctr);
        float v0 = vc.x, v1 = vc.y, v2 = vc.z;
        float w0 = wc.x, w1 = wc.y, w2 = wc.z;
        const int* ip = idx + ((size_t)b * N + n) * KNN;

        float a0 = 0.f, a1 = 0.f, a2 = 0.f;
        for (int kk = 0; kk < KNN; ++kk) {
            int m = ip[kk];
            size_t nb = ((size_t)(b * N + m) * Co + o) * 3;
            F3 un = *(const F3*)(U + nb);
            F3 dn = *(const F3*)(UD + nb);
            float p0 = un.x + v0;
            float p1 = un.y + v1;
            float p2 = un.z + v2;
            float nm = sqrtf(p0 * p0 + p1 * p1 + p2 * p2) + EPSV;
            float nbn = (nm - mu) * inv * gmm + bt;
            float sc = nbn / nm;
            p0 *= sc; p1 *= sc; p2 *= sc;
            float d0 = dn.x + w0;
            float d1 = dn.y + w1;
            float d2 = dn.z + w2;
            float dot = p0 * d0 + p1 * d1 + p2 * d2;
            if (dot >= 0.f) {
                a0 += p0; a1 += p1; a2 += p2;
            } else {
                float f = dot / (d0 * d0 + d1 * d1 + d2 * d2 + EPSV);
                a0 += NS * p0 + (1.f - NS) * (p0 - f * d0);
                a1 += NS * p1 + (1.f - NS) * (p1 - f * d1);
                a2 += NS * p2 + (1.f - NS) * (p2 - f * d2);
            }
        }
        tile[nl * CC + o * 3 + 0] = a0 * invk;
        tile[nl * CC + o * 3 + 1] = a1 * invk;
        tile[nl * CC + o * 3 + 2] = a2 * invk;
    }
    __syncthreads();

    for (int t = tid; t < TN * CC; t += 256) {
        int nl = t / CC, c = t - nl * CC;
        catp[(size_t)(b * N + n0 + nl) * CROW + colOff + c] = tile[nl * CC + c];
    }
    for (int t = tid; t < TN * CC; t += 256) {
        int c = t >> 3, nl = t & (TN - 1);   // TN == 8
        catn[(size_t)b * CROW * N + (size_t)(colOff + c) * N + n0 + nl] = tile[nl * CC + c];
    }
    if (doSq && tid < TN) {
        const float* row = tile + tid * CC;
        float s = 0.f;
        for (int c = 0; c < CC; ++c) {
            float v = row[c];
            s += v * v;
        }
        xx[(size_t)b * N + n0 + tid] = s;
    }
}

// ---------------- plain matmul (layer 5, n-major): U = W*x, j-fused + 2-n tile ----------
__global__ void k_matmul_plain(const float* __restrict__ X, const float* __restrict__ W,
                               const float* __restrict__ Dw,
                               float* __restrict__ U, float* __restrict__ Ud,
                               int N, int Cin, int Cout, long batchStride, long sliceOff) {
    int ot = blockIdx.y;
    int b = blockIdx.z;
    int tid = threadIdx.x;
    int n = blockIdx.x * 512 + 2 * tid;

    const float* Wp; float* Up; int CoutE; int o0;
    if (ot == (int)gridDim.y - 1) {   // Dw path
        Wp = Dw; Up = Ud; CoutE = 1; o0 = 0;
    } else {
        Wp = W; Up = U; CoutE = Cout; o0 = ot * OT;
    }

    __shared__ __align__(16) float wsm[OT][176];
    for (int t = tid; t < OT * Cin; t += 256) {
        int oo = t / Cin, c = t % Cin;
        int o = o0 + oo;
        wsm[oo][c] = (o < CoutE) ? Wp[(size_t)o * Cin + c] : 0.f;
    }
    __syncthreads();

    const float* Xp = X + (size_t)b * batchStride + sliceOff + n;
    float au[OT][3][2];
#pragma unroll
    for (int oo = 0; oo < OT; ++oo)
#pragma unroll
        for (int j = 0; j < 3; ++j) {
            au[oo][j][0] = 0.f; au[oo][j][1] = 0.f;
        }

    int c = 0;
    for (; c + 4 <= Cin; c += 4) {
        float2 xv[4][3];
#pragma unroll
        for (int cc = 0; cc < 4; ++cc)
#pragma unroll
            for (int j = 0; j < 3; ++j)
                xv[cc][j] = *(const float2*)(Xp + ((size_t)(c + cc) * 3 + j) * N);
#pragma unroll
        for (int oo = 0; oo < OT; ++oo) {
            float4 w4 = *(const float4*)&wsm[oo][c];
            float wv[4] = {w4.x, w4.y, w4.z, w4.w};
#pragma unroll
            for (int j = 0; j < 3; ++j) {
#pragma unroll
                for (int cc = 0; cc < 4; ++cc) {
                    au[oo][j][0] += wv[cc] * xv[cc][j].x;
                    au[oo][j][1] += wv[cc] * xv[cc][j].y;
                }
            }
        }
    }
    for (; c < Cin; ++c) {
        float2 xv[3];
#pragma unroll
        for (int j = 0; j < 3; ++j)
            xv[j] = *(const float2*)(Xp + ((size_t)c * 3 + j) * N);
#pragma unroll
        for (int oo = 0; oo < OT; ++oo) {
            float wv = wsm[oo][c];
#pragma unroll
            for (int j = 0; j < 3; ++j) {
                au[oo][j][0] += wv * xv[j].x;
                au[oo][j][1] += wv * xv[j].y;
            }
        }
    }
#pragma unroll
    for (int oo = 0; oo < OT; ++oo) {
        int o = o0 + oo;
        if (o < CoutE) {
#pragma unroll
            for (int j = 0; j < 3; ++j) {
                float2 st; st.x = au[oo][j][0]; st.y = au[oo][j][1];
                *(float2*)&Up[(((size_t)b * CoutE + o) * 3 + j) * N + n] = st;
            }
        }
    }
}

// ---------------- layer-5 stats (deterministic): one block per channel ----------------
__global__ void k_stats_plain_det(const float* __restrict__ U, float* __restrict__ mv,
                                  int N, int Cout, int BN, float cnt) {
    int o = blockIdx.x;
    int tid = threadIdx.x;
    float s1 = 0.f, s2 = 0.f;
    for (int g = tid; g < BN; g += 256) {
        int b = g / N, n = g % N;
        const float* Ub = U + (((size_t)b * Cout + o) * 3) * N;
        float p0 = Ub[n], p1 = Ub[(size_t)N + n], p2 = Ub[(size_t)2 * N + n];
        float nm = sqrtf(p0 * p0 + p1 * p1 + p2 * p2) + EPSV;
        s1 += nm;
        s2 += nm * nm;
    }
    __shared__ float r1[256], r2[256];
    r1[tid] = s1; r2[tid] = s2;
    __syncthreads();
    for (int st = 128; st > 0; st >>= 1) {
        if (tid < st) { r1[tid] += r1[tid + st]; r2[tid] += r2[tid + st]; }
        __syncthreads();
    }
    if (tid == 0) {
        float mu = r1[0] / cnt;
        float var = r2[0] / cnt - mu * mu;
        mv[2 * o] = mu;
        mv[2 * o + 1] = rsqrtf(var + 1e-5f);
    }
}

// ---------------- layer-5 final: BN + dir leaky (1 dir channel) -> d_out ----------------
__global__ void k_final_plain(const float* __restrict__ U, const float* __restrict__ Dv,
                              const float* __restrict__ mv,
                              const float* __restrict__ gamma, const float* __restrict__ beta,
                              float* __restrict__ out, int N, int Cout) {
    int b = blockIdx.z, o = blockIdx.y, tid = threadIdx.x;
    int n = blockIdx.x * 256 + tid;
    float mu = mv[2 * o];
    float inv = mv[2 * o + 1];
    float g = gamma[o], bt = beta[o];

    const float* Ub = U + (((size_t)b * Cout + o) * 3) * N;
    float p0 = Ub[n], p1 = Ub[(size_t)N + n], p2 = Ub[(size_t)2 * N + n];
    float nm = sqrtf(p0 * p0 + p1 * p1 + p2 * p2) + EPSV;
    float nbn = (nm - mu) * inv * g + bt;
    float sc = nbn / nm;
    p0 *= sc; p1 *= sc; p2 *= sc;

    float d0 = Dv[((size_t)b * 3 + 0) * N + n];
    float d1 = Dv[((size_t)b * 3 + 1) * N + n];
    float d2 = Dv[((size_t)b * 3 + 2) * N + n];
    float dot = p0 * d0 + p1 * d1 + p2 * d2;
    float o0, o1, o2;
    if (dot >= 0.f) {
        o0 = p0; o1 = p1; o2 = p2;
    } else {
        float f = dot / (d0 * d0 + d1 * d1 + d2 * d2 + EPSV);
        o0 = NS * p0 + (1.f - NS) * (p0 - f * d0);
        o1 = NS * p1 + (1.f - NS) * (p1 - f * d1);
        o2 = NS * p2 + (1.f - NS) * (p2 - f * d2);
    }
    size_t ob = (((size_t)b * Cout + o) * 3) * N + n;
    out[ob] = o0;
    out[ob + (size_t)N] = o1;
    out[ob + (size_t)2 * N] = o2;
}

extern "C" void kernel_launch(void* const* d_in, const int* in_sizes, int n_in,
                              void* d_out, int out_size, void* d_ws, size_t ws_size,
                              hipStream_t stream) {
    (void)in_sizes; (void)n_in; (void)out_size; (void)ws_size;
    const int B = 8, N = 1024;

    const float* x = (const float*)d_in[0];
    const float* W[5]; const float* Dw[5]; const float* G[5]; const float* Bt[5];
    for (int l = 0; l < 5; ++l) {
        W[l]  = (const float*)d_in[1 + 4 * l];
        Dw[l] = (const float*)d_in[2 + 4 * l];
        G[l]  = (const float*)d_in[3 + 4 * l];
        Bt[l] = (const float*)d_in[4 + 4 * l];
    }

    float* ws = (float*)d_ws;
    size_t off = 0;
    float* xt = ws + off;     off += (size_t)B * 3 * N;
    int* idx = (int*)(ws + off); off += (size_t)B * N * KNN;
    float* catp = ws + off;   off += (size_t)B * N * CROW;
    float* catn = ws + off;   off += (size_t)B * N * CROW;
    float* Up = ws + off;     off += (size_t)B * N * 85 * 3;
    float* Vp = ws + off;     off += (size_t)B * N * 85 * 3;
    float* UDp = ws + off;    off += (size_t)B * N * 85 * 3;
    float* VDp = ws + off;    off += (size_t)B * N * 85 * 3;
    float* U5 = ws + off;     off += (size_t)B * 341 * 3 * N;
    float* d5buf = ws + off;  off += (size_t)B * 3 * N;
    float* xx = ws + off;     off += (size_t)B * N;
    float* partials = ws + off; off += (size_t)341 * SSPLIT * 2;
    float* mv = ws + off;     off += 2 * 341;

    k_transpose<<<(B * N + 255) / 256, 256, 0, stream>>>(x, xt, xx, B, N);

    const int Cin_[4]  = {1, 21, 21, 42};
    const int Cout_[4] = {21, 21, 42, 85};
    const int inOff_[4] = {-1, 0, 21, 42};
    const int outOff_[4] = {0, 21, 42, 84};
    const int Tile_[4] = {32, 32, 16, 8};   // L3 TILE=16 to fit fused-LDS; L4 separate

    const int BN = B * N;
    const size_t KNN_LDS = (size_t)(128 * QT + QT * 1024) * sizeof(float);   // 18432

    for (int l = 0; l < 4; ++l) {
        int C = Cin_[l], Co = Cout_[l];
        int D = C * 3;
        int CoP = (Co + 3) & ~3;
        int TILE = Tile_[l];

        const float* Xn; long bs, so;
        if (inOff_[l] < 0) { Xn = xt; bs = (long)3 * N; so = 0; }
        else { Xn = catn; bs = (long)CROW * N; so = (long)inOff_[l] * 3 * N; }

        const float* Xp; int rs, co;
        if (inOff_[l] < 0) { Xp = x; rs = 3; co = 0; }
        else { Xp = catp; rs = CROW; co = inOff_[l] * 3; }

        size_t mmNeed = (size_t)(4 * C * CoP + TILE * C * 3) * sizeof(float);

        if (l < 3) {
            // fused: mm blocks first (overlap in knn's shadow), knn 8 queries/block
            int mmB = BN / TILE;
            int knnB = BN / 8;               // qPerBlock = 8
            size_t smemB = mmNeed > KNN_LDS ? mmNeed : KNN_LDS;
            k_knn_mm<<<mmB + knnB, 256, smemB, stream>>>(
                Xn, xx, idx, N, D, bs, so, 8,
                Xp, W[l], Dw[l], Up, Vp, UDp, VDp, C, Co, CoP, TILE, rs, co, mmB);
        } else {
            // L4: knn alone (qPerBlock=4, full 2048 blocks), mm separate (62KB LDS)
            k_knn_mm<<<BN / 4, 256, KNN_LDS, stream>>>(
                Xn, xx, idx, N, D, bs, so, 4,
                Xp, W[l], Dw[l], Up, Vp, UDp, VDp, C, Co, CoP, TILE, rs, co, 0);
            k_matmul_pair_lds<<<BN / TILE, 256, mmNeed, stream>>>(
                Xp, W[l], Dw[l], Up, Vp, UDp, VDp, C, Co, CoP, TILE, rs, co);
        }

        dim3 gst(Co, SSPLIT);
        k_stats_edge_det<<<gst, 256, 0, stream>>>(Up, Vp, idx, partials, N, Co, BN);

        int doSq = (l < 3) ? 1 : 0;
        dim3 gf(N / TN, B);
        k_final_fused<<<gf, 256, 0, stream>>>(
            Up, Vp, UDp, VDp, idx, partials, G[l], Bt[l],
            catp, catn, xx, N, Co, outOff_[l] * 3,
            (float)((size_t)BN * KNN), doSq);
    }

    // layer 5 (reads catn n-major); W and Dw matmuls merged into one launch
    {
        long bs = (long)CROW * N, so = 0;
        dim3 gm5(N / 512, (341 + OT - 1) / OT + 1, B);   // +1: Dw tile
        k_matmul_plain<<<gm5, 256, 0, stream>>>(catn, W[4], Dw[4], U5, d5buf,
                                                N, 169, 341, bs, so);
        k_stats_plain_det<<<341, 256, 0, stream>>>(U5, mv, N, 341, BN, (float)BN);
        dim3 gs5(N / 256, 341, B);
        k_final_plain<<<gs5, 256, 0, stream>>>(U5, d5buf, mv, G[4], Bt[4],
                                               (float*)d_out, N, 341);
    }
}